// Round 1
// baseline (871.258 us; speedup 1.0000x reference)
//
#include <hip/hip_runtime.h>
#include <hip/hip_bf16.h>
#include <math.h>

#define DIMSZ 1024
#define NHEAD 16
#define HDIM 64
#define FFDIM 4096
#define SEQ 2048
#define NBATCH 2

typedef unsigned short ushortt;
typedef __attribute__((ext_vector_type(8))) short frag8;   // 8 bf16 (4 VGPR)
typedef __attribute__((ext_vector_type(4))) float f32x4;   // MFMA acc

// bf16 (stored as ushort) <-> fp32
__device__ __forceinline__ float u2f(ushortt u) {
  return __uint_as_float(((unsigned)u) << 16);
}
__device__ __forceinline__ ushortt f2bu(float f) {  // RNE
  unsigned x = __float_as_uint(f);
  return (ushortt)((x + 0x7FFFu + ((x >> 16) & 1u)) >> 16);
}

// ---------------------------------------------------------------------------
// fp32 -> bf16 cast, 4 elems/thread, n % 4 == 0
// ---------------------------------------------------------------------------
__global__ __launch_bounds__(256) void cast_f2b(
    const float* __restrict__ src, ushortt* __restrict__ dst, int n) {
  int i = (blockIdx.x * 256 + threadIdx.x) * 4;
  if (i >= n) return;
  float4 f = *(const float4*)(src + i);
  ushort4 u;
  u.x = f2bu(f.x); u.y = f2bu(f.y); u.z = f2bu(f.z); u.w = f2bu(f.w);
  *(ushort4*)(dst + i) = u;
}

// ---------------------------------------------------------------------------
// Per-FF-chunk weight cast: gate rows (contig), lin rows (contig),
// ff_out_w cols c*1024.. (strided, row stride FFDIM) -> compact [1024][1024].
// ---------------------------------------------------------------------------
__global__ __launch_bounds__(256) void cast_ff_chunk(
    const float* __restrict__ gate_w, const float* __restrict__ lin_w,
    const float* __restrict__ ffout_w, int c,
    ushortt* __restrict__ gcb, ushortt* __restrict__ lcb,
    ushortt* __restrict__ focb) {
  const int M1 = 1048576;
  int t = (blockIdx.x * 256 + threadIdx.x) * 4;
  const float* src;
  ushortt* dst;
  int e;
  if (t < M1) {
    e = t; src = gate_w + (size_t)c * M1 + e; dst = gcb + e;
  } else if (t < 2 * M1) {
    e = t - M1; src = lin_w + (size_t)c * M1 + e; dst = lcb + e;
  } else {
    e = t - 2 * M1;
    int n = e >> 10, k = e & 1023;
    src = ffout_w + (size_t)n * FFDIM + c * 1024 + k; dst = focb + e;
  }
  float4 f = *(const float4*)src;
  ushort4 u;
  u.x = f2bu(f.x); u.y = f2bu(f.y); u.z = f2bu(f.z); u.w = f2bu(f.w);
  *(ushort4*)dst = u;
}

// ---------------------------------------------------------------------------
// MFMA GEMM (m97 pattern), unchanged.
// EPI: 0 fp32 store | 1 bf16 store | 2 sigmoid(acc+bias)->bf16
//      3 (acc+bias)*other->bf16    | 4 fp32 accumulate (first ? = : +=)
// ---------------------------------------------------------------------------
template <int EPI>
__global__ __launch_bounds__(256) void gemm_mfma(
    const ushortt* __restrict__ A, const ushortt* __restrict__ W,
    void* __restrict__ Cv, const float* __restrict__ bias,
    const ushortt* __restrict__ other, int M, int N, int K, int first) {
  __shared__ __align__(16) short As[128 * 32];
  __shared__ __align__(16) short Bs[128 * 32];
  const int tid = threadIdx.x;
  const int wave = tid >> 6;
  const int lane = tid & 63;
  const int bm = blockIdx.y * 128;
  const int bn = blockIdx.x * 128;
  const int wm = (wave >> 1) * 64;
  const int wn = (wave & 1) * 64;

  f32x4 acc[4][4] = {};

  const int sr = lane >> 2;
  const int sc = (lane & 3) * 8;
  const ushortt* pa0 = A + (size_t)(bm + wave * 16 + sr) * K + sc;
  const ushortt* pa1 = pa0 + (size_t)64 * K;
  const ushortt* pb0 = W + (size_t)(bn + wave * 16 + sr) * K + sc;
  const ushortt* pb1 = pb0 + (size_t)64 * K;
  short* la0 = &As[(wave * 16) * 32];
  short* la1 = &As[(64 + wave * 16) * 32];
  short* lb0 = &Bs[(wave * 16) * 32];
  short* lb1 = &Bs[(64 + wave * 16) * 32];

  const int fr = lane & 15;
  const int fq = (lane >> 4) * 8;

  for (int k0 = 0; k0 < K; k0 += 32) {
    __builtin_amdgcn_global_load_lds(
        (const __attribute__((address_space(1))) void*)(pa0 + k0),
        (__attribute__((address_space(3))) void*)la0, 16, 0, 0);
    __builtin_amdgcn_global_load_lds(
        (const __attribute__((address_space(1))) void*)(pa1 + k0),
        (__attribute__((address_space(3))) void*)la1, 16, 0, 0);
    __builtin_amdgcn_global_load_lds(
        (const __attribute__((address_space(1))) void*)(pb0 + k0),
        (__attribute__((address_space(3))) void*)lb0, 16, 0, 0);
    __builtin_amdgcn_global_load_lds(
        (const __attribute__((address_space(1))) void*)(pb1 + k0),
        (__attribute__((address_space(3))) void*)lb1, 16, 0, 0);
    __syncthreads();

    frag8 af[4], bf[4];
#pragma unroll
    for (int mi = 0; mi < 4; ++mi)
      af[mi] = *(const frag8*)&As[(wm + mi * 16 + fr) * 32 + fq];
#pragma unroll
    for (int ni = 0; ni < 4; ++ni)
      bf[ni] = *(const frag8*)&Bs[(wn + ni * 16 + fr) * 32 + fq];
#pragma unroll
    for (int mi = 0; mi < 4; ++mi)
#pragma unroll
      for (int ni = 0; ni < 4; ++ni)
        acc[mi][ni] = __builtin_amdgcn_mfma_f32_16x16x32_bf16(
            af[mi], bf[ni], acc[mi][ni], 0, 0, 0);
    __syncthreads();
  }

  const int er = (lane >> 4) * 4;
  const int ec = lane & 15;
#pragma unroll
  for (int mi = 0; mi < 4; ++mi)
#pragma unroll
    for (int ni = 0; ni < 4; ++ni)
#pragma unroll
      for (int r = 0; r < 4; ++r) {
        int m = bm + wm + mi * 16 + er + r;
        int n = bn + wn + ni * 16 + ec;
        size_t o = (size_t)m * N + n;
        float v = acc[mi][ni][r];
        if (EPI == 0) {
          ((float*)Cv)[o] = v;
        } else if (EPI == 1) {
          ((ushortt*)Cv)[o] = f2bu(v);
        } else if (EPI == 2) {
          v += bias[n];
          v = 1.0f / (1.0f + __expf(-v));
          ((ushortt*)Cv)[o] = f2bu(v);
        } else if (EPI == 3) {
          v = (v + bias[n]) * u2f(other[o]);
          ((ushortt*)Cv)[o] = f2bu(v);
        } else {
          float* C = (float*)Cv;
          C[o] = first ? v : C[o] + v;
        }
      }
}

// ---------------------------------------------------------------------------
// RoPE prep: qkv (B,S,3,H,D) bf16 -> Qr,Kr [bh][S][64] (Q scaled 1/8),
// Vr chunk-blocked [bh][S/64][64 d][64 key] (transposed per 64-seq chunk,
// so flash PV B-fragments read contiguous 2KB tiles, like K).
// One block per (64-seq tile, bh).
// ---------------------------------------------------------------------------
__global__ __launch_bounds__(256) void rope_prep(
    const ushortt* __restrict__ qkv, ushortt* __restrict__ Qr,
    ushortt* __restrict__ Kr, ushortt* __restrict__ Vr) {
  const int s0 = blockIdx.x * 64;
  const int bh = blockIdx.y;
  const int b = bh >> 4, h = bh & 15;
  const int tid = threadIdx.x;
  __shared__ float ifr_s[32];
  __shared__ ushortt vt[64][72];
  if (tid < 32) ifr_s[tid] = __powf(10000.0f, -(float)tid * (1.0f / 32.0f));
  __syncthreads();
  const size_t qbase = (size_t)bh * SEQ * 64;

  // Q,K RoPE: 64 rows x 32 pairs
#pragma unroll
  for (int i = 0; i < 8; ++i) {
    int p = i * 256 + tid;
    int r = p >> 5, d = p & 31;
    size_t src = ((size_t)(b * SEQ + s0 + r)) * (3 * DIMSZ) + h * 64 + d;
    float q1 = u2f(qkv[src]), q2 = u2f(qkv[src + 32]);
    float k1 = u2f(qkv[src + DIMSZ]), k2 = u2f(qkv[src + DIMSZ + 32]);
    float ang = (float)(s0 + r) * ifr_s[d];
    float sn, cs;
    __sincosf(ang, &sn, &cs);
    size_t dst = qbase + (size_t)(s0 + r) * 64 + d;
    Qr[dst]      = f2bu((q1 * cs - q2 * sn) * 0.125f);
    Qr[dst + 32] = f2bu((q1 * sn + q2 * cs) * 0.125f);
    Kr[dst]      = f2bu(k1 * cs - k2 * sn);
    Kr[dst + 32] = f2bu(k1 * sn + k2 * cs);
  }

  // V: stage 64x64 tile, write transposed rows into chunk-blocked layout
#pragma unroll
  for (int i = 0; i < 2; ++i) {
    int e = (i * 256 + tid) * 8;
    int r = e >> 6, d0 = e & 63;
    size_t src = ((size_t)(b * SEQ + s0 + r)) * (3 * DIMSZ) + 2 * DIMSZ + h * 64 + d0;
    *(ushort4*)&vt[r][d0]     = *(const ushort4*)(qkv + src);
    *(ushort4*)&vt[r][d0 + 4] = *(const ushort4*)(qkv + src + 4);
  }
  __syncthreads();
  {
    int d = tid >> 2;
    int sc0 = (tid & 3) * 16;
    // chunk-blocked: [bh][s0/64][d][key]
    size_t dst = (size_t)bh * 64 * SEQ + (size_t)blockIdx.x * 4096 +
                 (size_t)d * 64 + sc0;
    ushortt tmp[16];
#pragma unroll
    for (int j = 0; j < 16; ++j) tmp[j] = vt[sc0 + j][d];
    *(ushort4*)(Vr + dst)      = *(ushort4*)&tmp[0];
    *(ushort4*)(Vr + dst + 4)  = *(ushort4*)&tmp[4];
    *(ushort4*)(Vr + dst + 8)  = *(ushort4*)&tmp[8];
    *(ushort4*)(Vr + dst + 12) = *(ushort4*)&tmp[12];
  }
}

// ---------------------------------------------------------------------------
// MFMA flash attention, split-K across 2 wave-groups.
// Grid (SEQ/64, B*H), 512 thr = 8 waves. Wave w: group g=w>>2 processes
// chunks c0 = g*64, g*64+128, ... (even/odd interleave halves the serial
// chain and doubles resident waves); row-tile ws=w&3 owns 16 q-rows.
// Each group keeps private (m,l,O); LDS merge at the end.
// V is chunk-blocked [bh][chunk][d][key] -> contiguous 2KB fragment tiles.
// ---------------------------------------------------------------------------
__global__ __launch_bounds__(512) void flash_mfma(
    const ushortt* __restrict__ Qr, const ushortt* __restrict__ Kr,
    const ushortt* __restrict__ Vr, ushortt* __restrict__ ctx) {
  const int q0 = blockIdx.x * 64;
  const int bh = blockIdx.y;
  const int b = bh >> 4, h = bh & 15;
  const int tid = threadIdx.x;
  const int w = tid >> 6;
  const int g = w >> 2;        // chunk-parity group (0: even chunks, 1: odd)
  const int ws = w & 3;        // 16-row tile within the 64-row q-block
  const int lane = tid & 63;
  const int fr = lane & 15;
  const int quad = lane >> 4;

  // smem: during loop = 2x Ps[64][72] (one per group, 9216 B each);
  // after the first barrier = merge buffer [4 waves][64 lanes][25 floats]
  __shared__ __align__(16) char smem[25600];
  ushortt (*Ps)[72] = (ushortt(*)[72])(smem + g * 9216);

  const size_t qkbase = (size_t)bh * SEQ * 64;
  const size_t vbase = (size_t)bh * 64 * SEQ;

  // Q fragments: held in registers for the whole kernel
  frag8 aq[2];
#pragma unroll
  for (int hh = 0; hh < 2; ++hh)
    aq[hh] = *(const frag8*)(Qr + qkbase + (size_t)(q0 + ws * 16 + fr) * 64 +
                             hh * 32 + quad * 8);

  float mr[4], lr[4];
  f32x4 od[4] = {};  // od[dtile][reg]; C-layout row = quad*4+reg, col = dt*16+fr
#pragma unroll
  for (int r = 0; r < 4; ++r) { mr[r] = -1e30f; lr[r] = 0.0f; }

  for (int c0 = g * 64; c0 <= q0; c0 += 128) {
    // ---- S = Q K^T (A=Q[m][d], B=K[n][d]) ----
    f32x4 sc[4] = {};
#pragma unroll
    for (int ni = 0; ni < 4; ++ni)
#pragma unroll
      for (int hh = 0; hh < 2; ++hh) {
        frag8 kf = *(const frag8*)(Kr + qkbase +
                    (size_t)(c0 + ni * 16 + fr) * 64 + hh * 32 + quad * 8);
        sc[ni] = __builtin_amdgcn_mfma_f32_16x16x32_bf16(aq[hh], kf, sc[ni], 0, 0, 0);
      }

    // ---- causal mask (diagonal chunk only) ----
    if (c0 == q0) {
      int rowb = ws * 16 + quad * 4;
#pragma unroll
      for (int ni = 0; ni < 4; ++ni) {
        int col = ni * 16 + fr;
#pragma unroll
        for (int r = 0; r < 4; ++r)
          if (rowb + r < col) sc[ni][r] = -1e30f;
      }
    }

    // ---- online softmax per row (C-layout: quad's 16 lanes hold the row) ----
#pragma unroll
    for (int r = 0; r < 4; ++r) {
      float cm = fmaxf(fmaxf(sc[0][r], sc[1][r]), fmaxf(sc[2][r], sc[3][r]));
      for (int off = 1; off < 16; off <<= 1) cm = fmaxf(cm, __shfl_xor(cm, off, 16));
      float mn = fmaxf(mr[r], cm);
      float corr = __expf(mr[r] - mn);
      mr[r] = mn;
      float ps = 0.0f;
#pragma unroll
      for (int ni = 0; ni < 4; ++ni) {
        float p = __expf(sc[ni][r] - mn);
        Ps[ws * 16 + quad * 4 + r][ni * 16 + fr] = f2bu(p);
        ps += p;
      }
      for (int off = 1; off < 16; off <<= 1) ps += __shfl_xor(ps, off, 16);
      lr[r] = lr[r] * corr + ps;
#pragma unroll
      for (int dt = 0; dt < 4; ++dt) od[dt][r] *= corr;
    }
    // wave-local Ps rows: in-order wave + lgkmcnt => no barrier needed

    // ---- O += P V (A=P[m][key], B=Vchunk[d][key], contiguous tile) ----
    frag8 pf[2];
#pragma unroll
    for (int hh = 0; hh < 2; ++hh)
      pf[hh] = *(const frag8*)&Ps[ws * 16 + fr][hh * 32 + quad * 8];
#pragma unroll
    for (int dt = 0; dt < 4; ++dt)
#pragma unroll
      for (int hh = 0; hh < 2; ++hh) {
        frag8 vf = *(const frag8*)(Vr + vbase + (size_t)c0 * 64 +
                                   (size_t)(dt * 16 + fr) * 64 + hh * 32 + quad * 8);
        od[dt] = __builtin_amdgcn_mfma_f32_16x16x32_bf16(pf[hh], vf, od[dt], 0, 0, 0);
      }
  }

  // ---- merge the two chunk-parity groups, then write ctx (B,S,DIM) bf16 ----
  __syncthreads();  // all waves done with Ps
  if (g == 1) {
    float* p = (float*)smem + (ws * 64 + lane) * 25;
#pragma unroll
    for (int r = 0; r < 4; ++r) { p[r] = mr[r]; p[4 + r] = lr[r]; }
#pragma unroll
    for (int dt = 0; dt < 4; ++dt)
#pragma unroll
      for (int r = 0; r < 4; ++r) p[8 + dt * 4 + r] = od[dt][r];
  }
  __syncthreads();
  if (g == 0) {
    const float* p = (const float*)smem + (ws * 64 + lane) * 25;
#pragma unroll
    for (int r = 0; r < 4; ++r) {
      float m1 = p[r], l1 = p[4 + r];
      float mn = fmaxf(mr[r], m1);
      float c0f = __expf(mr[r] - mn);
      float c1f = __expf(m1 - mn);
      float inv = 1.0f / (lr[r] * c0f + l1 * c1f);
      size_t row = (size_t)(b * SEQ + q0 + ws * 16 + quad * 4 + r) * DIMSZ + h * 64;
#pragma unroll
      for (int dt = 0; dt < 4; ++dt)
        ctx[row + dt * 16 + fr] =
            f2bu((od[dt][r] * c0f + p[8 + dt * 4 + r] * c1f) * inv);
    }
  }
}

// ---------------------------------------------------------------------------
// y = res + proj; out = scale * y / (||y||*D^-0.5 + eps). One block per row.
// DUAL=1 also writes bf16 copy (GEMM A operand).
// ---------------------------------------------------------------------------
template <int DUAL>
__global__ __launch_bounds__(256) void add_rmsnorm(
    const float* __restrict__ res, const float* __restrict__ proj,
    const float* __restrict__ scale, float* __restrict__ out,
    ushortt* __restrict__ out2) {
  const int row = blockIdx.x;
  const int tid = threadIdx.x;
  const size_t base = (size_t)row * DIMSZ;
  __shared__ float red[4];
  float y[4];
  float ss = 0.0f;
#pragma unroll
  for (int j = 0; j < 4; ++j) {
    int d = tid + j * 256;
    float yv = res[base + d] + proj[base + d];
    y[j] = yv;
    ss += yv * yv;
  }
  for (int off = 1; off < 64; off <<= 1) ss += __shfl_xor(ss, off, 64);
  if ((tid & 63) == 0) red[tid >> 6] = ss;
  __syncthreads();
  float tot = red[0] + red[1] + red[2] + red[3];
  float norm = sqrtf(tot) * 0.03125f;
  float inv = 1.0f / (norm + 1e-8f);
#pragma unroll
  for (int j = 0; j < 4; ++j) {
    int d = tid + j * 256;
    float v = scale[d] * y[j] * inv;
    out[base + d] = v;
    if (DUAL) out2[base + d] = f2bu(v);
  }
}

// ---------------------------------------------------------------------------
extern "C" void kernel_launch(void* const* d_in, const int* in_sizes, int n_in,
                              void* d_out, int out_size, void* d_ws, size_t ws_size,
                              hipStream_t stream) {
  const float* x          = (const float*)d_in[0];
  // d_in[1] = causal mask (bool) — structure hardcoded, unused
  const float* qkv_w      = (const float*)d_in[2];
  const float* attn_out_w = (const float*)d_in[3];
  const float* gate_w     = (const float*)d_in[4];
  const float* gate_b     = (const float*)d_in[5];
  const float* lin_w      = (const float*)d_in[6];
  const float* lin_b      = (const float*)d_in[7];
  const float* ff_out_w   = (const float*)d_in[8];
  const float* n1s        = (const float*)d_in[9];
  const float* n2s        = (const float*)d_in[10];
  float* out = (float*)d_out;

  const int M = NBATCH * SEQ;  // 4096
  char* ws = (char*)d_ws;
  char* dob = (char*)d_out;
  const size_t MB = 1 << 20;
  // ws layout (bytes), lifetime-disjoint; high-water 48 MB (< proven 50.3):
  ushortt* qkv_tmp = (ushortt*)(ws + 0);        // [0,24)  bf16, p1..rope
  ushortt* xb      = (ushortt*)(ws + 24 * MB);  // [24,32) bf16, p1 (pre-Qr)
  ushortt* qkv_wb  = (ushortt*)(ws + 32 * MB);  // [32,38) bf16, p1 (pre-Kr)
  ushortt* Qr      = (ushortt*)(ws + 24 * MB);  // [24,32) bf16, rope..attn
  ushortt* Kr      = (ushortt*)(ws + 32 * MB);  // [32,40) bf16, rope..attn
  ushortt* Vr      = (ushortt*)(ws + 40 * MB);  // [40,48) bf16, rope..attn
  ushortt* attn_wb = (ushortt*)(ws + 24 * MB);  // [24,26) bf16, p3 (Qr dead)
  float*   proj    = (float*)(ws + 0);          // [0,16)  fp32, p3..p4 (qkv dead)
  float*   x1      = (float*)(ws + 16 * MB);    // [16,32) fp32, p4..end
  ushortt* x1b     = (ushortt*)(ws + 32 * MB);  // [32,40) bf16, p4..end (Kr dead)
  float*   proj2   = (float*)(ws + 0);          // [0,16)  fp32, p5..end
  ushortt* gcb     = (ushortt*)(ws + 40 * MB);  // [40,42) bf16, p5 chunk (Vr dead)
  ushortt* lcb     = (ushortt*)(ws + 42 * MB);  // [42,44)
  ushortt* focb    = (ushortt*)(ws + 44 * MB);  // [44,46)
  // d_out doubles as scratch:
  ushortt* ctx  = (ushortt*)(dob + 0);          // [0,8)  bf16, p2..p3
  ushortt* ffc  = (ushortt*)(dob + 0);          // [0,8)  bf16, p5 chunk
  ushortt* gtmp = (ushortt*)(dob + 8 * MB);     // [8,16) bf16, p5 chunk

  // p1: casts + qkv GEMM (bf16 out)
  cast_f2b<<<4194304 / 1024, 256, 0, stream>>>(x, xb, 4194304);
  cast_f2b<<<3145728 / 1024, 256, 0, stream>>>(qkv_w, qkv_wb, 3145728);
  gemm_mfma<1><<<dim3(3072 / 128, M / 128), 256, 0, stream>>>(
      xb, qkv_wb, qkv_tmp, nullptr, nullptr, M, 3072, DIMSZ, 0);
  // p2: RoPE prep + MFMA flash attention (8-wave split-K blocks)
  rope_prep<<<dim3(SEQ / 64, NBATCH * NHEAD), 256, 0, stream>>>(
      qkv_tmp, Qr, Kr, Vr);
  flash_mfma<<<dim3(SEQ / 64, NBATCH * NHEAD), 512, 0, stream>>>(
      Qr, Kr, Vr, ctx);
  // p3: attn projection (fp32 out)
  cast_f2b<<<1048576 / 1024, 256, 0, stream>>>(attn_out_w, attn_wb, 1048576);
  gemm_mfma<0><<<dim3(DIMSZ / 128, M / 128), 256, 0, stream>>>(
      ctx, attn_wb, proj, nullptr, nullptr, M, DIMSZ, DIMSZ, 0);
  // p4: x1 = rmsnorm(x + proj), fp32 + bf16 copies
  add_rmsnorm<1><<<M, 256, 0, stream>>>(x, proj, n1s, x1, x1b);
  // p5: FF in 4 chunks of 1024; proj2 accumulates fp32
  for (int c = 0; c < 4; ++c) {
    cast_ff_chunk<<<3072, 256, 0, stream>>>(gate_w, lin_w, ff_out_w, c,
                                            gcb, lcb, focb);
    gemm_mfma<2><<<dim3(1024 / 128, M / 128), 256, 0, stream>>>(
        x1b, gcb, gtmp, gate_b + c * 1024, nullptr, M, 1024, DIMSZ, 0);
    gemm_mfma<3><<<dim3(1024 / 128, M / 128), 256, 0, stream>>>(
        x1b, lcb, ffc, lin_b + c * 1024, gtmp, M, 1024, DIMSZ, 0);
    gemm_mfma<4><<<dim3(DIMSZ / 128, M / 128), 256, 0, stream>>>(
        ffc, focb, proj2, nullptr, nullptr, M, DIMSZ, 1024, c == 0 ? 1 : 0);
  }
  // p6: out = rmsnorm(x1 + proj2)
  add_rmsnorm<0><<<M, 256, 0, stream>>>(x1, proj2, n2s, out, nullptr);
}

// Round 2
// 787.617 us; speedup vs baseline: 1.1062x; 1.1062x over previous
//
#include <hip/hip_runtime.h>
#include <hip/hip_bf16.h>
#include <math.h>

#define DIMSZ 1024
#define NHEAD 16
#define HDIM 64
#define FFDIM 4096
#define SEQ 2048
#define NBATCH 2

typedef unsigned short ushortt;
typedef __attribute__((ext_vector_type(8))) short frag8;   // 8 bf16 (4 VGPR)
typedef __attribute__((ext_vector_type(4))) float f32x4;   // MFMA acc

// bf16 (stored as ushort) <-> fp32
__device__ __forceinline__ float u2f(ushortt u) {
  return __uint_as_float(((unsigned)u) << 16);
}
__device__ __forceinline__ ushortt f2bu(float f) {  // RNE
  unsigned x = __float_as_uint(f);
  return (ushortt)((x + 0x7FFFu + ((x >> 16) & 1u)) >> 16);
}

// ---------------------------------------------------------------------------
// fp32 -> bf16 cast, 4 elems/thread, n % 4 == 0
// ---------------------------------------------------------------------------
__global__ __launch_bounds__(256) void cast_f2b(
    const float* __restrict__ src, ushortt* __restrict__ dst, int n) {
  int i = (blockIdx.x * 256 + threadIdx.x) * 4;
  if (i >= n) return;
  float4 f = *(const float4*)(src + i);
  ushort4 u;
  u.x = f2bu(f.x); u.y = f2bu(f.y); u.z = f2bu(f.z); u.w = f2bu(f.w);
  *(ushort4*)(dst + i) = u;
}

// ---------------------------------------------------------------------------
// Per-FF-chunk weight cast: gate rows (contig), lin rows (contig),
// ff_out_w cols c*1024.. (strided, row stride FFDIM) -> compact [1024][1024].
// ---------------------------------------------------------------------------
__global__ __launch_bounds__(256) void cast_ff_chunk(
    const float* __restrict__ gate_w, const float* __restrict__ lin_w,
    const float* __restrict__ ffout_w, int c,
    ushortt* __restrict__ gcb, ushortt* __restrict__ lcb,
    ushortt* __restrict__ focb) {
  const int M1 = 1048576;
  int t = (blockIdx.x * 256 + threadIdx.x) * 4;
  const float* src;
  ushortt* dst;
  int e;
  if (t < M1) {
    e = t; src = gate_w + (size_t)c * M1 + e; dst = gcb + e;
  } else if (t < 2 * M1) {
    e = t - M1; src = lin_w + (size_t)c * M1 + e; dst = lcb + e;
  } else {
    e = t - 2 * M1;
    int n = e >> 10, k = e & 1023;
    src = ffout_w + (size_t)n * FFDIM + c * 1024 + k; dst = focb + e;
  }
  float4 f = *(const float4*)src;
  ushort4 u;
  u.x = f2bu(f.x); u.y = f2bu(f.y); u.z = f2bu(f.z); u.w = f2bu(f.w);
  *(ushort4*)dst = u;
}

// ---------------------------------------------------------------------------
// MFMA GEMM (m97 pattern), unchanged.
// EPI: 0 fp32 store | 1 bf16 store | 2 sigmoid(acc+bias)->bf16
//      3 (acc+bias)*other->bf16    | 4 fp32 accumulate (first ? = : +=)
// ---------------------------------------------------------------------------
template <int EPI>
__global__ __launch_bounds__(256) void gemm_mfma(
    const ushortt* __restrict__ A, const ushortt* __restrict__ W,
    void* __restrict__ Cv, const float* __restrict__ bias,
    const ushortt* __restrict__ other, int M, int N, int K, int first) {
  __shared__ __align__(16) short As[128 * 32];
  __shared__ __align__(16) short Bs[128 * 32];
  const int tid = threadIdx.x;
  const int wave = tid >> 6;
  const int lane = tid & 63;
  const int bm = blockIdx.y * 128;
  const int bn = blockIdx.x * 128;
  const int wm = (wave >> 1) * 64;
  const int wn = (wave & 1) * 64;

  f32x4 acc[4][4] = {};

  const int sr = lane >> 2;
  const int sc = (lane & 3) * 8;
  const ushortt* pa0 = A + (size_t)(bm + wave * 16 + sr) * K + sc;
  const ushortt* pa1 = pa0 + (size_t)64 * K;
  const ushortt* pb0 = W + (size_t)(bn + wave * 16 + sr) * K + sc;
  const ushortt* pb1 = pb0 + (size_t)64 * K;
  short* la0 = &As[(wave * 16) * 32];
  short* la1 = &As[(64 + wave * 16) * 32];
  short* lb0 = &Bs[(wave * 16) * 32];
  short* lb1 = &Bs[(64 + wave * 16) * 32];

  const int fr = lane & 15;
  const int fq = (lane >> 4) * 8;

  for (int k0 = 0; k0 < K; k0 += 32) {
    __builtin_amdgcn_global_load_lds(
        (const __attribute__((address_space(1))) void*)(pa0 + k0),
        (__attribute__((address_space(3))) void*)la0, 16, 0, 0);
    __builtin_amdgcn_global_load_lds(
        (const __attribute__((address_space(1))) void*)(pa1 + k0),
        (__attribute__((address_space(3))) void*)la1, 16, 0, 0);
    __builtin_amdgcn_global_load_lds(
        (const __attribute__((address_space(1))) void*)(pb0 + k0),
        (__attribute__((address_space(3))) void*)lb0, 16, 0, 0);
    __builtin_amdgcn_global_load_lds(
        (const __attribute__((address_space(1))) void*)(pb1 + k0),
        (__attribute__((address_space(3))) void*)lb1, 16, 0, 0);
    __syncthreads();

    frag8 af[4], bf[4];
#pragma unroll
    for (int mi = 0; mi < 4; ++mi)
      af[mi] = *(const frag8*)&As[(wm + mi * 16 + fr) * 32 + fq];
#pragma unroll
    for (int ni = 0; ni < 4; ++ni)
      bf[ni] = *(const frag8*)&Bs[(wn + ni * 16 + fr) * 32 + fq];
#pragma unroll
    for (int mi = 0; mi < 4; ++mi)
#pragma unroll
      for (int ni = 0; ni < 4; ++ni)
        acc[mi][ni] = __builtin_amdgcn_mfma_f32_16x16x32_bf16(
            af[mi], bf[ni], acc[mi][ni], 0, 0, 0);
    __syncthreads();
  }

  const int er = (lane >> 4) * 4;
  const int ec = lane & 15;
#pragma unroll
  for (int mi = 0; mi < 4; ++mi)
#pragma unroll
    for (int ni = 0; ni < 4; ++ni)
#pragma unroll
      for (int r = 0; r < 4; ++r) {
        int m = bm + wm + mi * 16 + er + r;
        int n = bn + wn + ni * 16 + ec;
        size_t o = (size_t)m * N + n;
        float v = acc[mi][ni][r];
        if (EPI == 0) {
          ((float*)Cv)[o] = v;
        } else if (EPI == 1) {
          ((ushortt*)Cv)[o] = f2bu(v);
        } else if (EPI == 2) {
          v += bias[n];
          v = 1.0f / (1.0f + __expf(-v));
          ((ushortt*)Cv)[o] = f2bu(v);
        } else if (EPI == 3) {
          v = (v + bias[n]) * u2f(other[o]);
          ((ushortt*)Cv)[o] = f2bu(v);
        } else {
          float* C = (float*)Cv;
          C[o] = first ? v : C[o] + v;
        }
      }
}

// ---------------------------------------------------------------------------
// RoPE prep: qkv (B,S,3,H,D) bf16 -> Qr,Kr [bh][S][64] (Q scaled 1/8),
// Vr chunk-blocked [bh][S/64][64 d][64 key] (transposed per 64-seq chunk,
// so flash PV B-fragments read contiguous 2KB tiles, like K).
// One block per (64-seq tile, bh).
// ---------------------------------------------------------------------------
__global__ __launch_bounds__(256) void rope_prep(
    const ushortt* __restrict__ qkv, ushortt* __restrict__ Qr,
    ushortt* __restrict__ Kr, ushortt* __restrict__ Vr) {
  const int s0 = blockIdx.x * 64;
  const int bh = blockIdx.y;
  const int b = bh >> 4, h = bh & 15;
  const int tid = threadIdx.x;
  __shared__ float ifr_s[32];
  __shared__ ushortt vt[64][72];
  if (tid < 32) ifr_s[tid] = __powf(10000.0f, -(float)tid * (1.0f / 32.0f));
  __syncthreads();
  const size_t qbase = (size_t)bh * SEQ * 64;

  // Q,K RoPE: 64 rows x 32 pairs
#pragma unroll
  for (int i = 0; i < 8; ++i) {
    int p = i * 256 + tid;
    int r = p >> 5, d = p & 31;
    size_t src = ((size_t)(b * SEQ + s0 + r)) * (3 * DIMSZ) + h * 64 + d;
    float q1 = u2f(qkv[src]), q2 = u2f(qkv[src + 32]);
    float k1 = u2f(qkv[src + DIMSZ]), k2 = u2f(qkv[src + DIMSZ + 32]);
    float ang = (float)(s0 + r) * ifr_s[d];
    float sn, cs;
    __sincosf(ang, &sn, &cs);
    size_t dst = qbase + (size_t)(s0 + r) * 64 + d;
    Qr[dst]      = f2bu((q1 * cs - q2 * sn) * 0.125f);
    Qr[dst + 32] = f2bu((q1 * sn + q2 * cs) * 0.125f);
    Kr[dst]      = f2bu(k1 * cs - k2 * sn);
    Kr[dst + 32] = f2bu(k1 * sn + k2 * cs);
  }

  // V: stage 64x64 tile, write transposed rows into chunk-blocked layout
#pragma unroll
  for (int i = 0; i < 2; ++i) {
    int e = (i * 256 + tid) * 8;
    int r = e >> 6, d0 = e & 63;
    size_t src = ((size_t)(b * SEQ + s0 + r)) * (3 * DIMSZ) + 2 * DIMSZ + h * 64 + d0;
    *(ushort4*)&vt[r][d0]     = *(const ushort4*)(qkv + src);
    *(ushort4*)&vt[r][d0 + 4] = *(const ushort4*)(qkv + src + 4);
  }
  __syncthreads();
  {
    int d = tid >> 2;
    int sc0 = (tid & 3) * 16;
    // chunk-blocked: [bh][s0/64][d][key]
    size_t dst = (size_t)bh * 64 * SEQ + (size_t)blockIdx.x * 4096 +
                 (size_t)d * 64 + sc0;
    ushortt tmp[16];
#pragma unroll
    for (int j = 0; j < 16; ++j) tmp[j] = vt[sc0 + j][d];
    *(ushort4*)(Vr + dst)      = *(ushort4*)&tmp[0];
    *(ushort4*)(Vr + dst + 4)  = *(ushort4*)&tmp[4];
    *(ushort4*)(Vr + dst + 8)  = *(ushort4*)&tmp[8];
    *(ushort4*)(Vr + dst + 12) = *(ushort4*)&tmp[12];
  }
}

// ---------------------------------------------------------------------------
// MFMA flash attention, split-K across 2 wave-groups.
// 1D grid of 1024 blocks, 512 thr = 8 waves. Block id decodes as
//   qt = id >> 5 (q-tile), bh = id & 31.
// This spreads causal-triangle cost across CUs: with XCD round-robin each CU
// hosts ids {c, c+256, c+512, c+768} -> qt spread {q,q+8,q+16,q+24} (cost
// ratio worst/avg 1.21 vs 32x when qt == id&31), and all 4 blocks share one
// bh -> same Kr/Vr working set in L1/L2.
// Wave w: group g=w>>2 processes chunks c0 = g*64, g*64+128, ...; row-tile
// ws=w&3 owns 16 q-rows. Each group keeps private (m,l,O); LDS merge at end.
// V is chunk-blocked [bh][chunk][d][key] -> contiguous 2KB fragment tiles.
// ---------------------------------------------------------------------------
__global__ __launch_bounds__(512) void flash_mfma(
    const ushortt* __restrict__ Qr, const ushortt* __restrict__ Kr,
    const ushortt* __restrict__ Vr, ushortt* __restrict__ ctx) {
  const int qt = blockIdx.x >> 5;
  const int bh = blockIdx.x & 31;
  const int q0 = qt * 64;
  const int b = bh >> 4, h = bh & 15;
  const int tid = threadIdx.x;
  const int w = tid >> 6;
  const int g = w >> 2;        // chunk-parity group (0: even chunks, 1: odd)
  const int ws = w & 3;        // 16-row tile within the 64-row q-block
  const int lane = tid & 63;
  const int fr = lane & 15;
  const int quad = lane >> 4;

  // smem: during loop = 2x Ps[64][72] (one per group, 9216 B each);
  // after the first barrier = merge buffer [4 waves][64 lanes][25 floats]
  __shared__ __align__(16) char smem[25600];
  ushortt (*Ps)[72] = (ushortt(*)[72])(smem + g * 9216);

  const size_t qkbase = (size_t)bh * SEQ * 64;
  const size_t vbase = (size_t)bh * 64 * SEQ;

  // Q fragments: held in registers for the whole kernel
  frag8 aq[2];
#pragma unroll
  for (int hh = 0; hh < 2; ++hh)
    aq[hh] = *(const frag8*)(Qr + qkbase + (size_t)(q0 + ws * 16 + fr) * 64 +
                             hh * 32 + quad * 8);

  float mr[4], lr[4];
  f32x4 od[4] = {};  // od[dtile][reg]; C-layout row = quad*4+reg, col = dt*16+fr
#pragma unroll
  for (int r = 0; r < 4; ++r) { mr[r] = -1e30f; lr[r] = 0.0f; }

  for (int c0 = g * 64; c0 <= q0; c0 += 128) {
    // ---- S = Q K^T (A=Q[m][d], B=K[n][d]) ----
    f32x4 sc[4] = {};
#pragma unroll
    for (int ni = 0; ni < 4; ++ni)
#pragma unroll
      for (int hh = 0; hh < 2; ++hh) {
        frag8 kf = *(const frag8*)(Kr + qkbase +
                    (size_t)(c0 + ni * 16 + fr) * 64 + hh * 32 + quad * 8);
        sc[ni] = __builtin_amdgcn_mfma_f32_16x16x32_bf16(aq[hh], kf, sc[ni], 0, 0, 0);
      }

    // ---- causal mask (diagonal chunk only) ----
    if (c0 == q0) {
      int rowb = ws * 16 + quad * 4;
#pragma unroll
      for (int ni = 0; ni < 4; ++ni) {
        int col = ni * 16 + fr;
#pragma unroll
        for (int r = 0; r < 4; ++r)
          if (rowb + r < col) sc[ni][r] = -1e30f;
      }
    }

    // ---- online softmax per row (C-layout: quad's 16 lanes hold the row) ----
#pragma unroll
    for (int r = 0; r < 4; ++r) {
      float cm = fmaxf(fmaxf(sc[0][r], sc[1][r]), fmaxf(sc[2][r], sc[3][r]));
      for (int off = 1; off < 16; off <<= 1) cm = fmaxf(cm, __shfl_xor(cm, off, 16));
      float mn = fmaxf(mr[r], cm);
      float corr = __expf(mr[r] - mn);
      mr[r] = mn;
      float ps = 0.0f;
#pragma unroll
      for (int ni = 0; ni < 4; ++ni) {
        float p = __expf(sc[ni][r] - mn);
        Ps[ws * 16 + quad * 4 + r][ni * 16 + fr] = f2bu(p);
        ps += p;
      }
      for (int off = 1; off < 16; off <<= 1) ps += __shfl_xor(ps, off, 16);
      lr[r] = lr[r] * corr + ps;
#pragma unroll
      for (int dt = 0; dt < 4; ++dt) od[dt][r] *= corr;
    }
    // wave-local Ps rows: in-order wave + lgkmcnt => no barrier needed

    // ---- O += P V (A=P[m][key], B=Vchunk[d][key], contiguous tile) ----
    frag8 pf[2];
#pragma unroll
    for (int hh = 0; hh < 2; ++hh)
      pf[hh] = *(const frag8*)&Ps[ws * 16 + fr][hh * 32 + quad * 8];
#pragma unroll
    for (int dt = 0; dt < 4; ++dt)
#pragma unroll
      for (int hh = 0; hh < 2; ++hh) {
        frag8 vf = *(const frag8*)(Vr + vbase + (size_t)c0 * 64 +
                                   (size_t)(dt * 16 + fr) * 64 + hh * 32 + quad * 8);
        od[dt] = __builtin_amdgcn_mfma_f32_16x16x32_bf16(pf[hh], vf, od[dt], 0, 0, 0);
      }
  }

  // ---- merge the two chunk-parity groups, then write ctx (B,S,DIM) bf16 ----
  __syncthreads();  // all waves done with Ps
  if (g == 1) {
    float* p = (float*)smem + (ws * 64 + lane) * 25;
#pragma unroll
    for (int r = 0; r < 4; ++r) { p[r] = mr[r]; p[4 + r] = lr[r]; }
#pragma unroll
    for (int dt = 0; dt < 4; ++dt)
#pragma unroll
      for (int r = 0; r < 4; ++r) p[8 + dt * 4 + r] = od[dt][r];
  }
  __syncthreads();
  if (g == 0) {
    const float* p = (const float*)smem + (ws * 64 + lane) * 25;
#pragma unroll
    for (int r = 0; r < 4; ++r) {
      float m1 = p[r], l1 = p[4 + r];
      float mn = fmaxf(mr[r], m1);
      float c0f = __expf(mr[r] - mn);
      float c1f = __expf(m1 - mn);
      float inv = 1.0f / (lr[r] * c0f + l1 * c1f);
      size_t row = (size_t)(b * SEQ + q0 + ws * 16 + quad * 4 + r) * DIMSZ + h * 64;
#pragma unroll
      for (int dt = 0; dt < 4; ++dt)
        ctx[row + dt * 16 + fr] =
            f2bu((od[dt][r] * c0f + p[8 + dt * 4 + r] * c1f) * inv);
    }
  }
}

// ---------------------------------------------------------------------------
// y = res + proj; out = scale * y / (||y||*D^-0.5 + eps). One block per row.
// DUAL=1 also writes bf16 copy (GEMM A operand).
// ---------------------------------------------------------------------------
template <int DUAL>
__global__ __launch_bounds__(256) void add_rmsnorm(
    const float* __restrict__ res, const float* __restrict__ proj,
    const float* __restrict__ scale, float* __restrict__ out,
    ushortt* __restrict__ out2) {
  const int row = blockIdx.x;
  const int tid = threadIdx.x;
  const size_t base = (size_t)row * DIMSZ;
  __shared__ float red[4];
  float y[4];
  float ss = 0.0f;
#pragma unroll
  for (int j = 0; j < 4; ++j) {
    int d = tid + j * 256;
    float yv = res[base + d] + proj[base + d];
    y[j] = yv;
    ss += yv * yv;
  }
  for (int off = 1; off < 64; off <<= 1) ss += __shfl_xor(ss, off, 64);
  if ((tid & 63) == 0) red[tid >> 6] = ss;
  __syncthreads();
  float tot = red[0] + red[1] + red[2] + red[3];
  float norm = sqrtf(tot) * 0.03125f;
  float inv = 1.0f / (norm + 1e-8f);
#pragma unroll
  for (int j = 0; j < 4; ++j) {
    int d = tid + j * 256;
    float v = scale[d] * y[j] * inv;
    out[base + d] = v;
    if (DUAL) out2[base + d] = f2bu(v);
  }
}

// ---------------------------------------------------------------------------
extern "C" void kernel_launch(void* const* d_in, const int* in_sizes, int n_in,
                              void* d_out, int out_size, void* d_ws, size_t ws_size,
                              hipStream_t stream) {
  const float* x          = (const float*)d_in[0];
  // d_in[1] = causal mask (bool) — structure hardcoded, unused
  const float* qkv_w      = (const float*)d_in[2];
  const float* attn_out_w = (const float*)d_in[3];
  const float* gate_w     = (const float*)d_in[4];
  const float* gate_b     = (const float*)d_in[5];
  const float* lin_w      = (const float*)d_in[6];
  const float* lin_b      = (const float*)d_in[7];
  const float* ff_out_w   = (const float*)d_in[8];
  const float* n1s        = (const float*)d_in[9];
  const float* n2s        = (const float*)d_in[10];
  float* out = (float*)d_out;

  const int M = NBATCH * SEQ;  // 4096
  char* ws = (char*)d_ws;
  char* dob = (char*)d_out;
  const size_t MB = 1 << 20;
  // ws layout (bytes), lifetime-disjoint; high-water 48 MB (< proven 50.3):
  ushortt* qkv_tmp = (ushortt*)(ws + 0);        // [0,24)  bf16, p1..rope
  ushortt* xb      = (ushortt*)(ws + 24 * MB);  // [24,32) bf16, p1 (pre-Qr)
  ushortt* qkv_wb  = (ushortt*)(ws + 32 * MB);  // [32,38) bf16, p1 (pre-Kr)
  ushortt* Qr      = (ushortt*)(ws + 24 * MB);  // [24,32) bf16, rope..attn
  ushortt* Kr      = (ushortt*)(ws + 32 * MB);  // [32,40) bf16, rope..attn
  ushortt* Vr      = (ushortt*)(ws + 40 * MB);  // [40,48) bf16, rope..attn
  ushortt* attn_wb = (ushortt*)(ws + 24 * MB);  // [24,26) bf16, p3 (Qr dead)
  float*   proj    = (float*)(ws + 0);          // [0,16)  fp32, p3..p4 (qkv dead)
  float*   x1      = (float*)(ws + 16 * MB);    // [16,32) fp32, p4..end
  ushortt* x1b     = (ushortt*)(ws + 32 * MB);  // [32,40) bf16, p4..end (Kr dead)
  float*   proj2   = (float*)(ws + 0);          // [0,16)  fp32, p5..end
  ushortt* gcb     = (ushortt*)(ws + 40 * MB);  // [40,42) bf16, p5 chunk (Vr dead)
  ushortt* lcb     = (ushortt*)(ws + 42 * MB);  // [42,44)
  ushortt* focb    = (ushortt*)(ws + 44 * MB);  // [44,46)
  // d_out doubles as scratch:
  ushortt* ctx  = (ushortt*)(dob + 0);          // [0,8)  bf16, p2..p3
  ushortt* ffc  = (ushortt*)(dob + 0);          // [0,8)  bf16, p5 chunk
  ushortt* gtmp = (ushortt*)(dob + 8 * MB);     // [8,16) bf16, p5 chunk

  // p1: casts + qkv GEMM (bf16 out)
  cast_f2b<<<4194304 / 1024, 256, 0, stream>>>(x, xb, 4194304);
  cast_f2b<<<3145728 / 1024, 256, 0, stream>>>(qkv_w, qkv_wb, 3145728);
  gemm_mfma<1><<<dim3(3072 / 128, M / 128), 256, 0, stream>>>(
      xb, qkv_wb, qkv_tmp, nullptr, nullptr, M, 3072, DIMSZ, 0);
  // p2: RoPE prep + MFMA flash attention (8-wave split-K blocks, 1D grid
  // with cost-spreading qt/bh decode)
  rope_prep<<<dim3(SEQ / 64, NBATCH * NHEAD), 256, 0, stream>>>(
      qkv_tmp, Qr, Kr, Vr);
  flash_mfma<<<(SEQ / 64) * NBATCH * NHEAD, 512, 0, stream>>>(
      Qr, Kr, Vr, ctx);
  // p3: attn projection (fp32 out)
  cast_f2b<<<1048576 / 1024, 256, 0, stream>>>(attn_out_w, attn_wb, 1048576);
  gemm_mfma<0><<<dim3(DIMSZ / 128, M / 128), 256, 0, stream>>>(
      ctx, attn_wb, proj, nullptr, nullptr, M, DIMSZ, DIMSZ, 0);
  // p4: x1 = rmsnorm(x + proj), fp32 + bf16 copies
  add_rmsnorm<1><<<M, 256, 0, stream>>>(x, proj, n1s, x1, x1b);
  // p5: FF in 4 chunks of 1024; proj2 accumulates fp32
  for (int c = 0; c < 4; ++c) {
    cast_ff_chunk<<<3072, 256, 0, stream>>>(gate_w, lin_w, ff_out_w, c,
                                            gcb, lcb, focb);
    gemm_mfma<2><<<dim3(1024 / 128, M / 128), 256, 0, stream>>>(
        x1b, gcb, gtmp, gate_b + c * 1024, nullptr, M, 1024, DIMSZ, 0);
    gemm_mfma<3><<<dim3(1024 / 128, M / 128), 256, 0, stream>>>(
        x1b, lcb, ffc, lin_b + c * 1024, gtmp, M, 1024, DIMSZ, 0);
    gemm_mfma<4><<<dim3(DIMSZ / 128, M / 128), 256, 0, stream>>>(
        ffc, focb, proj2, nullptr, nullptr, M, DIMSZ, 1024, c == 0 ? 1 : 0);
  }
  // p6: out = rmsnorm(x1 + proj2)
  add_rmsnorm<0><<<M, 256, 0, stream>>>(x1, proj2, n2s, out, nullptr);
}

// Round 3
// 718.132 us; speedup vs baseline: 1.2132x; 1.0968x over previous
//
#include <hip/hip_runtime.h>
#include <hip/hip_bf16.h>
#include <math.h>

#define DIMSZ 1024
#define NHEAD 16
#define HDIM 64
#define FFDIM 4096
#define SEQ 2048
#define NBATCH 2

typedef unsigned short ushortt;
typedef __attribute__((ext_vector_type(8))) short frag8;   // 8 bf16 (4 VGPR)
typedef __attribute__((ext_vector_type(4))) float f32x4;   // MFMA acc

// bf16 (stored as ushort) <-> fp32
__device__ __forceinline__ float u2f(ushortt u) {
  return __uint_as_float(((unsigned)u) << 16);
}
__device__ __forceinline__ ushortt f2bu(float f) {  // RNE
  unsigned x = __float_as_uint(f);
  return (ushortt)((x + 0x7FFFu + ((x >> 16) & 1u)) >> 16);
}

// ---------------------------------------------------------------------------
// fp32 -> bf16 cast, 4 elems/thread, n % 4 == 0
// ---------------------------------------------------------------------------
__global__ __launch_bounds__(256) void cast_f2b(
    const float* __restrict__ src, ushortt* __restrict__ dst, int n) {
  int i = (blockIdx.x * 256 + threadIdx.x) * 4;
  if (i >= n) return;
  float4 f = *(const float4*)(src + i);
  ushort4 u;
  u.x = f2bu(f.x); u.y = f2bu(f.y); u.z = f2bu(f.z); u.w = f2bu(f.w);
  *(ushort4*)(dst + i) = u;
}

// ---------------------------------------------------------------------------
// Per-FF-chunk weight cast: gate rows (contig), lin rows (contig),
// ff_out_w cols c*1024.. (strided, row stride FFDIM) -> compact [1024][1024].
// ---------------------------------------------------------------------------
__global__ __launch_bounds__(256) void cast_ff_chunk(
    const float* __restrict__ gate_w, const float* __restrict__ lin_w,
    const float* __restrict__ ffout_w, int c,
    ushortt* __restrict__ gcb, ushortt* __restrict__ lcb,
    ushortt* __restrict__ focb) {
  const int M1 = 1048576;
  int t = (blockIdx.x * 256 + threadIdx.x) * 4;
  const float* src;
  ushortt* dst;
  int e;
  if (t < M1) {
    e = t; src = gate_w + (size_t)c * M1 + e; dst = gcb + e;
  } else if (t < 2 * M1) {
    e = t - M1; src = lin_w + (size_t)c * M1 + e; dst = lcb + e;
  } else {
    e = t - 2 * M1;
    int n = e >> 10, k = e & 1023;
    src = ffout_w + (size_t)n * FFDIM + c * 1024 + k; dst = focb + e;
  }
  float4 f = *(const float4*)src;
  ushort4 u;
  u.x = f2bu(f.x); u.y = f2bu(f.y); u.z = f2bu(f.z); u.w = f2bu(f.w);
  *(ushort4*)dst = u;
}

// ---------------------------------------------------------------------------
// MFMA GEMM (m97 pattern), unchanged.
// EPI: 0 fp32 store | 1 bf16 store | 2 sigmoid(acc+bias)->bf16
//      3 (acc+bias)*other->bf16    | 4 fp32 accumulate (first ? = : +=)
// ---------------------------------------------------------------------------
template <int EPI>
__global__ __launch_bounds__(256) void gemm_mfma(
    const ushortt* __restrict__ A, const ushortt* __restrict__ W,
    void* __restrict__ Cv, const float* __restrict__ bias,
    const ushortt* __restrict__ other, int M, int N, int K, int first) {
  __shared__ __align__(16) short As[128 * 32];
  __shared__ __align__(16) short Bs[128 * 32];
  const int tid = threadIdx.x;
  const int wave = tid >> 6;
  const int lane = tid & 63;
  const int bm = blockIdx.y * 128;
  const int bn = blockIdx.x * 128;
  const int wm = (wave >> 1) * 64;
  const int wn = (wave & 1) * 64;

  f32x4 acc[4][4] = {};

  const int sr = lane >> 2;
  const int sc = (lane & 3) * 8;
  const ushortt* pa0 = A + (size_t)(bm + wave * 16 + sr) * K + sc;
  const ushortt* pa1 = pa0 + (size_t)64 * K;
  const ushortt* pb0 = W + (size_t)(bn + wave * 16 + sr) * K + sc;
  const ushortt* pb1 = pb0 + (size_t)64 * K;
  short* la0 = &As[(wave * 16) * 32];
  short* la1 = &As[(64 + wave * 16) * 32];
  short* lb0 = &Bs[(wave * 16) * 32];
  short* lb1 = &Bs[(64 + wave * 16) * 32];

  const int fr = lane & 15;
  const int fq = (lane >> 4) * 8;

  for (int k0 = 0; k0 < K; k0 += 32) {
    __builtin_amdgcn_global_load_lds(
        (const __attribute__((address_space(1))) void*)(pa0 + k0),
        (__attribute__((address_space(3))) void*)la0, 16, 0, 0);
    __builtin_amdgcn_global_load_lds(
        (const __attribute__((address_space(1))) void*)(pa1 + k0),
        (__attribute__((address_space(3))) void*)la1, 16, 0, 0);
    __builtin_amdgcn_global_load_lds(
        (const __attribute__((address_space(1))) void*)(pb0 + k0),
        (__attribute__((address_space(3))) void*)lb0, 16, 0, 0);
    __builtin_amdgcn_global_load_lds(
        (const __attribute__((address_space(1))) void*)(pb1 + k0),
        (__attribute__((address_space(3))) void*)lb1, 16, 0, 0);
    __syncthreads();

    frag8 af[4], bf[4];
#pragma unroll
    for (int mi = 0; mi < 4; ++mi)
      af[mi] = *(const frag8*)&As[(wm + mi * 16 + fr) * 32 + fq];
#pragma unroll
    for (int ni = 0; ni < 4; ++ni)
      bf[ni] = *(const frag8*)&Bs[(wn + ni * 16 + fr) * 32 + fq];
#pragma unroll
    for (int mi = 0; mi < 4; ++mi)
#pragma unroll
      for (int ni = 0; ni < 4; ++ni)
        acc[mi][ni] = __builtin_amdgcn_mfma_f32_16x16x32_bf16(
            af[mi], bf[ni], acc[mi][ni], 0, 0, 0);
    __syncthreads();
  }

  const int er = (lane >> 4) * 4;
  const int ec = lane & 15;
#pragma unroll
  for (int mi = 0; mi < 4; ++mi)
#pragma unroll
    for (int ni = 0; ni < 4; ++ni)
#pragma unroll
      for (int r = 0; r < 4; ++r) {
        int m = bm + wm + mi * 16 + er + r;
        int n = bn + wn + ni * 16 + ec;
        size_t o = (size_t)m * N + n;
        float v = acc[mi][ni][r];
        if (EPI == 0) {
          ((float*)Cv)[o] = v;
        } else if (EPI == 1) {
          ((ushortt*)Cv)[o] = f2bu(v);
        } else if (EPI == 2) {
          v += bias[n];
          v = 1.0f / (1.0f + __expf(-v));
          ((ushortt*)Cv)[o] = f2bu(v);
        } else if (EPI == 3) {
          v = (v + bias[n]) * u2f(other[o]);
          ((ushortt*)Cv)[o] = f2bu(v);
        } else {
          float* C = (float*)Cv;
          C[o] = first ? v : C[o] + v;
        }
      }
}

// ---------------------------------------------------------------------------
// RoPE prep: qkv (B,S,3,H,D) bf16 -> Qr,Kr [bh][S][64] (Q scaled 1/8),
// Vr chunk-blocked [bh][S/64][64 d][64 key] (transposed per 64-seq chunk).
// One block per (64-seq tile, bh).
// ---------------------------------------------------------------------------
__global__ __launch_bounds__(256) void rope_prep(
    const ushortt* __restrict__ qkv, ushortt* __restrict__ Qr,
    ushortt* __restrict__ Kr, ushortt* __restrict__ Vr) {
  const int s0 = blockIdx.x * 64;
  const int bh = blockIdx.y;
  const int b = bh >> 4, h = bh & 15;
  const int tid = threadIdx.x;
  __shared__ float ifr_s[32];
  __shared__ ushortt vt[64][72];
  if (tid < 32) ifr_s[tid] = __powf(10000.0f, -(float)tid * (1.0f / 32.0f));
  __syncthreads();
  const size_t qbase = (size_t)bh * SEQ * 64;

  // Q,K RoPE: 64 rows x 32 pairs
#pragma unroll
  for (int i = 0; i < 8; ++i) {
    int p = i * 256 + tid;
    int r = p >> 5, d = p & 31;
    size_t src = ((size_t)(b * SEQ + s0 + r)) * (3 * DIMSZ) + h * 64 + d;
    float q1 = u2f(qkv[src]), q2 = u2f(qkv[src + 32]);
    float k1 = u2f(qkv[src + DIMSZ]), k2 = u2f(qkv[src + DIMSZ + 32]);
    float ang = (float)(s0 + r) * ifr_s[d];
    float sn, cs;
    __sincosf(ang, &sn, &cs);
    size_t dst = qbase + (size_t)(s0 + r) * 64 + d;
    Qr[dst]      = f2bu((q1 * cs - q2 * sn) * 0.125f);
    Qr[dst + 32] = f2bu((q1 * sn + q2 * cs) * 0.125f);
    Kr[dst]      = f2bu(k1 * cs - k2 * sn);
    Kr[dst + 32] = f2bu(k1 * sn + k2 * cs);
  }

  // V: stage 64x64 tile, write transposed rows into chunk-blocked layout
#pragma unroll
  for (int i = 0; i < 2; ++i) {
    int e = (i * 256 + tid) * 8;
    int r = e >> 6, d0 = e & 63;
    size_t src = ((size_t)(b * SEQ + s0 + r)) * (3 * DIMSZ) + 2 * DIMSZ + h * 64 + d0;
    *(ushort4*)&vt[r][d0]     = *(const ushort4*)(qkv + src);
    *(ushort4*)&vt[r][d0 + 4] = *(const ushort4*)(qkv + src + 4);
  }
  __syncthreads();
  {
    int d = tid >> 2;
    int sc0 = (tid & 3) * 16;
    // chunk-blocked: [bh][s0/64][d][key]
    size_t dst = (size_t)bh * 64 * SEQ + (size_t)blockIdx.x * 4096 +
                 (size_t)d * 64 + sc0;
    ushortt tmp[16];
#pragma unroll
    for (int j = 0; j < 16; ++j) tmp[j] = vt[sc0 + j][d];
    *(ushort4*)(Vr + dst)      = *(ushort4*)&tmp[0];
    *(ushort4*)(Vr + dst + 4)  = *(ushort4*)&tmp[4];
    *(ushort4*)(Vr + dst + 8)  = *(ushort4*)&tmp[8];
    *(ushort4*)(Vr + dst + 12) = *(ushort4*)&tmp[12];
  }
}

// ---------------------------------------------------------------------------
// MFMA flash attention, LDS-staged K/V with double-buffered prefetch.
// 1D grid of 512 blocks: qt = id>>5 (128-row q tile), bh = id&31.
// XCD round-robin gives each CU ids {c, c+256} -> qt {q, q+8}, SAME bh
// (shared K/V working set in L2). 512 thr = 8 waves; wave w owns q-rows
// w*16..w*16+15. All waves walk the same 64-key chunk sequence; each chunk's
// K (64x64) and V^T (64x64) are staged cooperatively into LDS via
// global_load_lds (1 instr/thread each), double-buffered: STAGE(t+1) is
// issued before compute(t) so global latency hides under MFMA+softmax.
// LDS tiles have 128B rows -> XOR-swizzle byte^=((row&7)<<4) applied on BOTH
// sides (pre-swizzled global source, swizzled ds_read) per rule #21.
// ---------------------------------------------------------------------------
__global__ __launch_bounds__(512) void flash_mfma(
    const ushortt* __restrict__ Qr, const ushortt* __restrict__ Kr,
    const ushortt* __restrict__ Vr, ushortt* __restrict__ ctx) {
  const int id = blockIdx.x;
  const int qt = id >> 5;
  const int bh = id & 31;
  const int q0 = qt * 128;
  const int b = bh >> 4, h = bh & 15;
  const int tid = threadIdx.x;
  const int w = tid >> 6;
  const int lane = tid & 63;
  const int fr = lane & 15;
  const int quad = lane >> 4;

  __shared__ __align__(16) short Kb[2][4096];     // 2 x 8KB: [key][dim]
  __shared__ __align__(16) short Vb[2][4096];     // 2 x 8KB: [dim][key]
  __shared__ __align__(16) ushortt Ps[8][16][72]; // per-wave P tiles

  const size_t qkbase = (size_t)bh * SEQ * 64;
  const size_t vbase = (size_t)bh * 64 * SEQ;

  // Per-lane pre-swizzled stage source (bytes within an 8KB chunk).
  // LDS dest is linear (wave base + lane*16); involution lin^((lin>>7&7)<<4).
  const int lin = (w << 10) + ((lane & 63) << 4);
  const int swz = lin ^ (((lin >> 7) & 7) << 4);
  const char* ksrc = (const char*)(Kr + qkbase) + swz;
  const char* vsrc = (const char*)(Vr + vbase) + swz;
  short* kdst[2] = {&Kb[0][w * 512], &Kb[1][w * 512]};
  short* vdst[2] = {&Vb[0][w * 512], &Vb[1][w * 512]};

  // Q fragments: registers for the whole kernel
  frag8 aq[2];
#pragma unroll
  for (int hh = 0; hh < 2; ++hh)
    aq[hh] = *(const frag8*)(Qr + qkbase + (size_t)(q0 + w * 16 + fr) * 64 +
                             hh * 32 + quad * 8);

  float mr[4], lr[4];
  f32x4 od[4] = {};  // od[dtile][reg]; row = quad*4+reg, col = dt*16+fr
#pragma unroll
  for (int r = 0; r < 4; ++r) { mr[r] = -1e30f; lr[r] = 0.0f; }

  const int nt = 2 * qt + 2;

  // prologue: stage chunk 0 into buffer 0
  __builtin_amdgcn_global_load_lds(
      (const __attribute__((address_space(1))) void*)ksrc,
      (__attribute__((address_space(3))) void*)kdst[0], 16, 0, 0);
  __builtin_amdgcn_global_load_lds(
      (const __attribute__((address_space(1))) void*)vsrc,
      (__attribute__((address_space(3))) void*)vdst[0], 16, 0, 0);
  __syncthreads();

  for (int t = 0; t < nt; ++t) {
    const int c0 = t * 64;
    // issue next chunk's stage before compute (hidden under compute(t))
    if (t + 1 < nt) {
      const char* kn = ksrc + (size_t)(t + 1) * 8192;
      const char* vn = vsrc + (size_t)(t + 1) * 8192;
      __builtin_amdgcn_global_load_lds(
          (const __attribute__((address_space(1))) void*)kn,
          (__attribute__((address_space(3))) void*)kdst[(t + 1) & 1], 16, 0, 0);
      __builtin_amdgcn_global_load_lds(
          (const __attribute__((address_space(1))) void*)vn,
          (__attribute__((address_space(3))) void*)vdst[(t + 1) & 1], 16, 0, 0);
    }
    const char* kcur = (const char*)Kb[t & 1];
    const char* vcur = (const char*)Vb[t & 1];

    // wave active iff chunk intersects this wave's causal range
    if (c0 <= q0 + w * 16 + 15) {
      // ---- S = Q K^T (A=Q[m][d], B=K[n][d], from swizzled LDS) ----
      f32x4 sc[4] = {};
#pragma unroll
      for (int ni = 0; ni < 4; ++ni)
#pragma unroll
        for (int hh = 0; hh < 2; ++hh) {
          int kb = (((ni * 16 + fr) << 7) + (hh << 6) + (quad << 4)) ^
                   ((fr & 7) << 4);
          frag8 kf = *(const frag8*)(kcur + kb);
          sc[ni] = __builtin_amdgcn_mfma_f32_16x16x32_bf16(aq[hh], kf, sc[ni],
                                                           0, 0, 0);
        }

      // ---- causal mask (only when chunk straddles the diagonal) ----
      if (c0 + 63 > q0 + w * 16) {
        int rowb = q0 + w * 16 + quad * 4;
#pragma unroll
        for (int ni = 0; ni < 4; ++ni) {
          int col = c0 + ni * 16 + fr;
#pragma unroll
          for (int r = 0; r < 4; ++r)
            if (col > rowb + r) sc[ni][r] = -1e30f;
        }
      }

      // ---- online softmax per row (quad's 16 lanes hold the row) ----
#pragma unroll
      for (int r = 0; r < 4; ++r) {
        float cm = fmaxf(fmaxf(sc[0][r], sc[1][r]), fmaxf(sc[2][r], sc[3][r]));
        for (int off = 1; off < 16; off <<= 1)
          cm = fmaxf(cm, __shfl_xor(cm, off, 16));
        float mn = fmaxf(mr[r], cm);
        float corr = __expf(mr[r] - mn);
        mr[r] = mn;
        float ps = 0.0f;
#pragma unroll
        for (int ni = 0; ni < 4; ++ni) {
          float p = __expf(sc[ni][r] - mn);
          Ps[w][quad * 4 + r][ni * 16 + fr] = f2bu(p);
          ps += p;
        }
        for (int off = 1; off < 16; off <<= 1) ps += __shfl_xor(ps, off, 16);
        lr[r] = lr[r] * corr + ps;
#pragma unroll
        for (int dt = 0; dt < 4; ++dt) od[dt][r] *= corr;
      }
      // wave-local Ps rows: in-order wave + lgkmcnt => no barrier needed

      // ---- O += P V (A=P[m][key], B=V^T[d][key], from swizzled LDS) ----
      frag8 pf[2];
#pragma unroll
      for (int hh = 0; hh < 2; ++hh)
        pf[hh] = *(const frag8*)&Ps[w][fr][hh * 32 + quad * 8];
#pragma unroll
      for (int dt = 0; dt < 4; ++dt)
#pragma unroll
        for (int hh = 0; hh < 2; ++hh) {
          int vb_ = (((dt * 16 + fr) << 7) + (hh << 6) + (quad << 4)) ^
                    ((fr & 7) << 4);
          frag8 vf = *(const frag8*)(vcur + vb_);
          od[dt] = __builtin_amdgcn_mfma_f32_16x16x32_bf16(pf[hh], vf, od[dt],
                                                           0, 0, 0);
        }
    }
    // barrier: drains stage(t+1) (vmcnt) + all waves done reading buf[t&1]
    __syncthreads();
  }

  // ---- write ctx (B,S,DIM) bf16 ----
#pragma unroll
  for (int r = 0; r < 4; ++r) {
    float inv = 1.0f / lr[r];
    size_t row = (size_t)(b * SEQ + q0 + w * 16 + quad * 4 + r) * DIMSZ + h * 64;
#pragma unroll
    for (int dt = 0; dt < 4; ++dt)
      ctx[row + dt * 16 + fr] = f2bu(od[dt][r] * inv);
  }
}

// ---------------------------------------------------------------------------
// y = res + proj; out = scale * y / (||y||*D^-0.5 + eps). One block per row.
// DUAL=1 also writes bf16 copy (GEMM A operand).
// ---------------------------------------------------------------------------
template <int DUAL>
__global__ __launch_bounds__(256) void add_rmsnorm(
    const float* __restrict__ res, const float* __restrict__ proj,
    const float* __restrict__ scale, float* __restrict__ out,
    ushortt* __restrict__ out2) {
  const int row = blockIdx.x;
  const int tid = threadIdx.x;
  const size_t base = (size_t)row * DIMSZ;
  __shared__ float red[4];
  float y[4];
  float ss = 0.0f;
#pragma unroll
  for (int j = 0; j < 4; ++j) {
    int d = tid + j * 256;
    float yv = res[base + d] + proj[base + d];
    y[j] = yv;
    ss += yv * yv;
  }
  for (int off = 1; off < 64; off <<= 1) ss += __shfl_xor(ss, off, 64);
  if ((tid & 63) == 0) red[tid >> 6] = ss;
  __syncthreads();
  float tot = red[0] + red[1] + red[2] + red[3];
  float norm = sqrtf(tot) * 0.03125f;
  float inv = 1.0f / (norm + 1e-8f);
#pragma unroll
  for (int j = 0; j < 4; ++j) {
    int d = tid + j * 256;
    float v = scale[d] * y[j] * inv;
    out[base + d] = v;
    if (DUAL) out2[base + d] = f2bu(v);
  }
}

// ---------------------------------------------------------------------------
extern "C" void kernel_launch(void* const* d_in, const int* in_sizes, int n_in,
                              void* d_out, int out_size, void* d_ws, size_t ws_size,
                              hipStream_t stream) {
  const float* x          = (const float*)d_in[0];
  // d_in[1] = causal mask (bool) — structure hardcoded, unused
  const float* qkv_w      = (const float*)d_in[2];
  const float* attn_out_w = (const float*)d_in[3];
  const float* gate_w     = (const float*)d_in[4];
  const float* gate_b     = (const float*)d_in[5];
  const float* lin_w      = (const float*)d_in[6];
  const float* lin_b      = (const float*)d_in[7];
  const float* ff_out_w   = (const float*)d_in[8];
  const float* n1s        = (const float*)d_in[9];
  const float* n2s        = (const float*)d_in[10];
  float* out = (float*)d_out;

  const int M = NBATCH * SEQ;  // 4096
  char* ws = (char*)d_ws;
  char* dob = (char*)d_out;
  const size_t MB = 1 << 20;
  // ws layout (bytes), lifetime-disjoint; high-water 48 MB (< proven 50.3):
  ushortt* qkv_tmp = (ushortt*)(ws + 0);        // [0,24)  bf16, p1..rope
  ushortt* xb      = (ushortt*)(ws + 24 * MB);  // [24,32) bf16, p1 (pre-Qr)
  ushortt* qkv_wb  = (ushortt*)(ws + 32 * MB);  // [32,38) bf16, p1 (pre-Kr)
  ushortt* Qr      = (ushortt*)(ws + 24 * MB);  // [24,32) bf16, rope..attn
  ushortt* Kr      = (ushortt*)(ws + 32 * MB);  // [32,40) bf16, rope..attn
  ushortt* Vr      = (ushortt*)(ws + 40 * MB);  // [40,48) bf16, rope..attn
  ushortt* attn_wb = (ushortt*)(ws + 24 * MB);  // [24,26) bf16, p3 (Qr dead)
  float*   proj    = (float*)(ws + 0);          // [0,16)  fp32, p3..p4 (qkv dead)
  float*   x1      = (float*)(ws + 16 * MB);    // [16,32) fp32, p4..end
  ushortt* x1b     = (ushortt*)(ws + 32 * MB);  // [32,40) bf16, p4..end (Kr dead)
  float*   proj2   = (float*)(ws + 0);          // [0,16)  fp32, p5..end
  ushortt* gcb     = (ushortt*)(ws + 40 * MB);  // [40,42) bf16, p5 chunk (Vr dead)
  ushortt* lcb     = (ushortt*)(ws + 42 * MB);  // [42,44)
  ushortt* focb    = (ushortt*)(ws + 44 * MB);  // [44,46)
  // d_out doubles as scratch:
  ushortt* ctx  = (ushortt*)(dob + 0);          // [0,8)  bf16, p2..p3
  ushortt* ffc  = (ushortt*)(dob + 0);          // [0,8)  bf16, p5 chunk
  ushortt* gtmp = (ushortt*)(dob + 8 * MB);     // [8,16) bf16, p5 chunk

  // p1: casts + qkv GEMM (bf16 out)
  cast_f2b<<<4194304 / 1024, 256, 0, stream>>>(x, xb, 4194304);
  cast_f2b<<<3145728 / 1024, 256, 0, stream>>>(qkv_w, qkv_wb, 3145728);
  gemm_mfma<1><<<dim3(3072 / 128, M / 128), 256, 0, stream>>>(
      xb, qkv_wb, qkv_tmp, nullptr, nullptr, M, 3072, DIMSZ, 0);
  // p2: RoPE prep + MFMA flash attention (LDS-staged, 512 blocks of 8 waves)
  rope_prep<<<dim3(SEQ / 64, NBATCH * NHEAD), 256, 0, stream>>>(
      qkv_tmp, Qr, Kr, Vr);
  flash_mfma<<<(SEQ / 128) * NBATCH * NHEAD, 512, 0, stream>>>(
      Qr, Kr, Vr, ctx);
  // p3: attn projection (fp32 out)
  cast_f2b<<<1048576 / 1024, 256, 0, stream>>>(attn_out_w, attn_wb, 1048576);
  gemm_mfma<0><<<dim3(DIMSZ / 128, M / 128), 256, 0, stream>>>(
      ctx, attn_wb, proj, nullptr, nullptr, M, DIMSZ, DIMSZ, 0);
  // p4: x1 = rmsnorm(x + proj), fp32 + bf16 copies
  add_rmsnorm<1><<<M, 256, 0, stream>>>(x, proj, n1s, x1, x1b);
  // p5: FF in 4 chunks of 1024; proj2 accumulates fp32
  for (int c = 0; c < 4; ++c) {
    cast_ff_chunk<<<3072, 256, 0, stream>>>(gate_w, lin_w, ff_out_w, c,
                                            gcb, lcb, focb);
    gemm_mfma<2><<<dim3(1024 / 128, M / 128), 256, 0, stream>>>(
        x1b, gcb, gtmp, gate_b + c * 1024, nullptr, M, 1024, DIMSZ, 0);
    gemm_mfma<3><<<dim3(1024 / 128, M / 128), 256, 0, stream>>>(
        x1b, lcb, ffc, lin_b + c * 1024, gtmp, M, 1024, DIMSZ, 0);
    gemm_mfma<4><<<dim3(DIMSZ / 128, M / 128), 256, 0, stream>>>(
        ffc, focb, proj2, nullptr, nullptr, M, DIMSZ, 1024, c == 0 ? 1 : 0);
  }
  // p6: out = rmsnorm(x1 + proj2)
  add_rmsnorm<0><<<M, 256, 0, stream>>>(x1, proj2, n2s, out, nullptr);
}

// Round 4
// 615.064 us; speedup vs baseline: 1.4165x; 1.1676x over previous
//
#include <hip/hip_runtime.h>
#include <hip/hip_bf16.h>
#include <math.h>

#define DIMSZ 1024
#define NHEAD 16
#define HDIM 64
#define FFDIM 4096
#define SEQ 2048
#define NBATCH 2

typedef unsigned short ushortt;
typedef __attribute__((ext_vector_type(8))) short frag8;   // 8 bf16 (4 VGPR)
typedef __attribute__((ext_vector_type(4))) float f32x4;   // MFMA acc

// bf16 (stored as ushort) <-> fp32
__device__ __forceinline__ float u2f(ushortt u) {
  return __uint_as_float(((unsigned)u) << 16);
}
__device__ __forceinline__ ushortt f2bu(float f) {  // RNE
  unsigned x = __float_as_uint(f);
  return (ushortt)((x + 0x7FFFu + ((x >> 16) & 1u)) >> 16);
}

// ---------------------------------------------------------------------------
// fp32 -> bf16 cast, 4 elems/thread, n % 4 == 0
// ---------------------------------------------------------------------------
__global__ __launch_bounds__(256) void cast_f2b(
    const float* __restrict__ src, ushortt* __restrict__ dst, int n) {
  int i = (blockIdx.x * 256 + threadIdx.x) * 4;
  if (i >= n) return;
  float4 f = *(const float4*)(src + i);
  ushort4 u;
  u.x = f2bu(f.x); u.y = f2bu(f.y); u.z = f2bu(f.z); u.w = f2bu(f.w);
  *(ushort4*)(dst + i) = u;
}

// ---------------------------------------------------------------------------
// Per-FF-chunk weight cast: gate rows (contig), lin rows (contig),
// ff_out_w cols c*1024.. (strided, row stride FFDIM) -> compact [1024][1024].
// ---------------------------------------------------------------------------
__global__ __launch_bounds__(256) void cast_ff_chunk(
    const float* __restrict__ gate_w, const float* __restrict__ lin_w,
    const float* __restrict__ ffout_w, int c,
    ushortt* __restrict__ gcb, ushortt* __restrict__ lcb,
    ushortt* __restrict__ focb) {
  const int M1 = 1048576;
  int t = (blockIdx.x * 256 + threadIdx.x) * 4;
  const float* src;
  ushortt* dst;
  int e;
  if (t < M1) {
    e = t; src = gate_w + (size_t)c * M1 + e; dst = gcb + e;
  } else if (t < 2 * M1) {
    e = t - M1; src = lin_w + (size_t)c * M1 + e; dst = lcb + e;
  } else {
    e = t - 2 * M1;
    int n = e >> 10, k = e & 1023;
    src = ffout_w + (size_t)n * FFDIM + c * 1024 + k; dst = focb + e;
  }
  float4 f = *(const float4*)src;
  ushort4 u;
  u.x = f2bu(f.x); u.y = f2bu(f.y); u.z = f2bu(f.z); u.w = f2bu(f.w);
  *(ushort4*)dst = u;
}

// ---------------------------------------------------------------------------
// MFMA GEMM, double-buffered: STAGE(t+1) issued before compute(t), single
// barrier per K-step (flash-proven pattern). Critical at 1 block/CU grids
// where no other block hides the staging latency.
// EPI: 0 fp32 store | 1 bf16 store | 4 fp32 accumulate (first ? = : +=)
// ---------------------------------------------------------------------------
template <int EPI>
__global__ __launch_bounds__(256) void gemm_mfma(
    const ushortt* __restrict__ A, const ushortt* __restrict__ W,
    void* __restrict__ Cv, const float* __restrict__ bias,
    const ushortt* __restrict__ other, int M, int N, int K, int first) {
  __shared__ __align__(16) short As[2][128 * 32];
  __shared__ __align__(16) short Bs[2][128 * 32];
  const int tid = threadIdx.x;
  const int wave = tid >> 6;
  const int lane = tid & 63;
  const int bm = blockIdx.y * 128;
  const int bn = blockIdx.x * 128;
  const int wm = (wave >> 1) * 64;
  const int wn = (wave & 1) * 64;

  f32x4 acc[4][4] = {};

  const int sr = lane >> 2;
  const int sc = (lane & 3) * 8;
  const ushortt* pa0 = A + (size_t)(bm + wave * 16 + sr) * K + sc;
  const ushortt* pa1 = pa0 + (size_t)64 * K;
  const ushortt* pb0 = W + (size_t)(bn + wave * 16 + sr) * K + sc;
  const ushortt* pb1 = pb0 + (size_t)64 * K;
  const int lo0 = (wave * 16) * 32;
  const int lo1 = (64 + wave * 16) * 32;

  const int fr = lane & 15;
  const int fq = (lane >> 4) * 8;
  const int nt = K >> 5;

  auto stage = [&](int t, int buf) {
    const int ko = t * 32;
    short* ab = &As[0][0] + buf * 4096;
    short* bb = &Bs[0][0] + buf * 4096;
    __builtin_amdgcn_global_load_lds(
        (const __attribute__((address_space(1))) void*)(pa0 + ko),
        (__attribute__((address_space(3))) void*)(ab + lo0), 16, 0, 0);
    __builtin_amdgcn_global_load_lds(
        (const __attribute__((address_space(1))) void*)(pa1 + ko),
        (__attribute__((address_space(3))) void*)(ab + lo1), 16, 0, 0);
    __builtin_amdgcn_global_load_lds(
        (const __attribute__((address_space(1))) void*)(pb0 + ko),
        (__attribute__((address_space(3))) void*)(bb + lo0), 16, 0, 0);
    __builtin_amdgcn_global_load_lds(
        (const __attribute__((address_space(1))) void*)(pb1 + ko),
        (__attribute__((address_space(3))) void*)(bb + lo1), 16, 0, 0);
  };

  stage(0, 0);
  __syncthreads();

  for (int t = 0; t < nt; ++t) {
    if (t + 1 < nt) stage(t + 1, (t + 1) & 1);
    const short* as = &As[0][0] + (t & 1) * 4096;
    const short* bs = &Bs[0][0] + (t & 1) * 4096;

    frag8 af[4], bf[4];
#pragma unroll
    for (int mi = 0; mi < 4; ++mi)
      af[mi] = *(const frag8*)&as[(wm + mi * 16 + fr) * 32 + fq];
#pragma unroll
    for (int ni = 0; ni < 4; ++ni)
      bf[ni] = *(const frag8*)&bs[(wn + ni * 16 + fr) * 32 + fq];
#pragma unroll
    for (int mi = 0; mi < 4; ++mi)
#pragma unroll
      for (int ni = 0; ni < 4; ++ni)
        acc[mi][ni] = __builtin_amdgcn_mfma_f32_16x16x32_bf16(
            af[mi], bf[ni], acc[mi][ni], 0, 0, 0);
    // barrier: drains stage(t+1) (vmcnt) + all waves done reading buf[t&1]
    __syncthreads();
  }

  const int er = (lane >> 4) * 4;
  const int ec = lane & 15;
#pragma unroll
  for (int mi = 0; mi < 4; ++mi)
#pragma unroll
    for (int ni = 0; ni < 4; ++ni)
#pragma unroll
      for (int r = 0; r < 4; ++r) {
        int m = bm + wm + mi * 16 + er + r;
        int n = bn + wn + ni * 16 + ec;
        size_t o = (size_t)m * N + n;
        float v = acc[mi][ni][r];
        if (EPI == 0) {
          ((float*)Cv)[o] = v;
        } else if (EPI == 1) {
          ((ushortt*)Cv)[o] = f2bu(v);
        } else {
          float* C = (float*)Cv;
          C[o] = first ? v : C[o] + v;
        }
      }
}

// ---------------------------------------------------------------------------
// Fused gate+lin GEMM: one staged A tile feeds TWO B tiles (gate, lin),
// 32 MFMA per K-step (2x compute under the same staging latency), dual
// accumulators. Epilogue: out = sigmoid(g + gbias) * (l + lbias) -> bf16.
// Eliminates the 16MB gtmp round-trip and 4 dispatches.
// ---------------------------------------------------------------------------
__global__ __launch_bounds__(256) void gemm_gatelin(
    const ushortt* __restrict__ A, const ushortt* __restrict__ Wg,
    const ushortt* __restrict__ Wl, ushortt* __restrict__ Cv,
    const float* __restrict__ gbias, const float* __restrict__ lbias,
    int M, int N, int K) {
  __shared__ __align__(16) short As[2][128 * 32];
  __shared__ __align__(16) short Gs[2][128 * 32];
  __shared__ __align__(16) short Ls[2][128 * 32];
  const int tid = threadIdx.x;
  const int wave = tid >> 6;
  const int lane = tid & 63;
  const int bm = blockIdx.y * 128;
  const int bn = blockIdx.x * 128;
  const int wm = (wave >> 1) * 64;
  const int wn = (wave & 1) * 64;

  f32x4 accg[4][4] = {};
  f32x4 accl[4][4] = {};

  const int sr = lane >> 2;
  const int sc = (lane & 3) * 8;
  const ushortt* pa0 = A + (size_t)(bm + wave * 16 + sr) * K + sc;
  const ushortt* pa1 = pa0 + (size_t)64 * K;
  const ushortt* pg0 = Wg + (size_t)(bn + wave * 16 + sr) * K + sc;
  const ushortt* pg1 = pg0 + (size_t)64 * K;
  const ushortt* pl0 = Wl + (size_t)(bn + wave * 16 + sr) * K + sc;
  const ushortt* pl1 = pl0 + (size_t)64 * K;
  const int lo0 = (wave * 16) * 32;
  const int lo1 = (64 + wave * 16) * 32;

  const int fr = lane & 15;
  const int fq = (lane >> 4) * 8;
  const int nt = K >> 5;

  auto stage = [&](int t, int buf) {
    const int ko = t * 32;
    short* ab = &As[0][0] + buf * 4096;
    short* gb = &Gs[0][0] + buf * 4096;
    short* lb = &Ls[0][0] + buf * 4096;
    __builtin_amdgcn_global_load_lds(
        (const __attribute__((address_space(1))) void*)(pa0 + ko),
        (__attribute__((address_space(3))) void*)(ab + lo0), 16, 0, 0);
    __builtin_amdgcn_global_load_lds(
        (const __attribute__((address_space(1))) void*)(pa1 + ko),
        (__attribute__((address_space(3))) void*)(ab + lo1), 16, 0, 0);
    __builtin_amdgcn_global_load_lds(
        (const __attribute__((address_space(1))) void*)(pg0 + ko),
        (__attribute__((address_space(3))) void*)(gb + lo0), 16, 0, 0);
    __builtin_amdgcn_global_load_lds(
        (const __attribute__((address_space(1))) void*)(pg1 + ko),
        (__attribute__((address_space(3))) void*)(gb + lo1), 16, 0, 0);
    __builtin_amdgcn_global_load_lds(
        (const __attribute__((address_space(1))) void*)(pl0 + ko),
        (__attribute__((address_space(3))) void*)(lb + lo0), 16, 0, 0);
    __builtin_amdgcn_global_load_lds(
        (const __attribute__((address_space(1))) void*)(pl1 + ko),
        (__attribute__((address_space(3))) void*)(lb + lo1), 16, 0, 0);
  };

  stage(0, 0);
  __syncthreads();

  for (int t = 0; t < nt; ++t) {
    if (t + 1 < nt) stage(t + 1, (t + 1) & 1);
    const short* as = &As[0][0] + (t & 1) * 4096;
    const short* gs = &Gs[0][0] + (t & 1) * 4096;
    const short* ls = &Ls[0][0] + (t & 1) * 4096;

    frag8 af[4], gf[4], lf[4];
#pragma unroll
    for (int mi = 0; mi < 4; ++mi)
      af[mi] = *(const frag8*)&as[(wm + mi * 16 + fr) * 32 + fq];
#pragma unroll
    for (int ni = 0; ni < 4; ++ni) {
      gf[ni] = *(const frag8*)&gs[(wn + ni * 16 + fr) * 32 + fq];
      lf[ni] = *(const frag8*)&ls[(wn + ni * 16 + fr) * 32 + fq];
    }
#pragma unroll
    for (int mi = 0; mi < 4; ++mi)
#pragma unroll
      for (int ni = 0; ni < 4; ++ni) {
        accg[mi][ni] = __builtin_amdgcn_mfma_f32_16x16x32_bf16(
            af[mi], gf[ni], accg[mi][ni], 0, 0, 0);
        accl[mi][ni] = __builtin_amdgcn_mfma_f32_16x16x32_bf16(
            af[mi], lf[ni], accl[mi][ni], 0, 0, 0);
      }
    __syncthreads();
  }

  const int er = (lane >> 4) * 4;
  const int ec = lane & 15;
#pragma unroll
  for (int mi = 0; mi < 4; ++mi)
#pragma unroll
    for (int ni = 0; ni < 4; ++ni)
#pragma unroll
      for (int r = 0; r < 4; ++r) {
        int m = bm + wm + mi * 16 + er + r;
        int n = bn + wn + ni * 16 + ec;
        size_t o = (size_t)m * N + n;
        float g = accg[mi][ni][r] + gbias[n];
        float l = accl[mi][ni][r] + lbias[n];
        float sig = 1.0f / (1.0f + __expf(-g));
        ((ushortt*)Cv)[o] = f2bu(sig * l);
      }
}

// ---------------------------------------------------------------------------
// RoPE prep: qkv (B,S,3,H,D) bf16 -> Qr,Kr [bh][S][64] (Q scaled 1/8),
// Vr chunk-blocked [bh][S/64][64 d][64 key] (transposed per 64-seq chunk).
// One block per (64-seq tile, bh).
// ---------------------------------------------------------------------------
__global__ __launch_bounds__(256) void rope_prep(
    const ushortt* __restrict__ qkv, ushortt* __restrict__ Qr,
    ushortt* __restrict__ Kr, ushortt* __restrict__ Vr) {
  const int s0 = blockIdx.x * 64;
  const int bh = blockIdx.y;
  const int b = bh >> 4, h = bh & 15;
  const int tid = threadIdx.x;
  __shared__ float ifr_s[32];
  __shared__ ushortt vt[64][72];
  if (tid < 32) ifr_s[tid] = __powf(10000.0f, -(float)tid * (1.0f / 32.0f));
  __syncthreads();
  const size_t qbase = (size_t)bh * SEQ * 64;

  // Q,K RoPE: 64 rows x 32 pairs
#pragma unroll
  for (int i = 0; i < 8; ++i) {
    int p = i * 256 + tid;
    int r = p >> 5, d = p & 31;
    size_t src = ((size_t)(b * SEQ + s0 + r)) * (3 * DIMSZ) + h * 64 + d;
    float q1 = u2f(qkv[src]), q2 = u2f(qkv[src + 32]);
    float k1 = u2f(qkv[src + DIMSZ]), k2 = u2f(qkv[src + DIMSZ + 32]);
    float ang = (float)(s0 + r) * ifr_s[d];
    float sn, cs;
    __sincosf(ang, &sn, &cs);
    size_t dst = qbase + (size_t)(s0 + r) * 64 + d;
    Qr[dst]      = f2bu((q1 * cs - q2 * sn) * 0.125f);
    Qr[dst + 32] = f2bu((q1 * sn + q2 * cs) * 0.125f);
    Kr[dst]      = f2bu(k1 * cs - k2 * sn);
    Kr[dst + 32] = f2bu(k1 * sn + k2 * cs);
  }

  // V: stage 64x64 tile, write transposed rows into chunk-blocked layout
#pragma unroll
  for (int i = 0; i < 2; ++i) {
    int e = (i * 256 + tid) * 8;
    int r = e >> 6, d0 = e & 63;
    size_t src = ((size_t)(b * SEQ + s0 + r)) * (3 * DIMSZ) + 2 * DIMSZ + h * 64 + d0;
    *(ushort4*)&vt[r][d0]     = *(const ushort4*)(qkv + src);
    *(ushort4*)&vt[r][d0 + 4] = *(const ushort4*)(qkv + src + 4);
  }
  __syncthreads();
  {
    int d = tid >> 2;
    int sc0 = (tid & 3) * 16;
    // chunk-blocked: [bh][s0/64][d][key]
    size_t dst = (size_t)bh * 64 * SEQ + (size_t)blockIdx.x * 4096 +
                 (size_t)d * 64 + sc0;
    ushortt tmp[16];
#pragma unroll
    for (int j = 0; j < 16; ++j) tmp[j] = vt[sc0 + j][d];
    *(ushort4*)(Vr + dst)      = *(ushort4*)&tmp[0];
    *(ushort4*)(Vr + dst + 4)  = *(ushort4*)&tmp[4];
    *(ushort4*)(Vr + dst + 8)  = *(ushort4*)&tmp[8];
    *(ushort4*)(Vr + dst + 12) = *(ushort4*)&tmp[12];
  }
}

// ---------------------------------------------------------------------------
// MFMA flash attention, LDS-staged K/V with double-buffered prefetch.
// 1D grid of 512 blocks: qt = id>>5 (128-row q tile), bh = id&31.
// XCD round-robin gives each CU ids {c, c+256} -> qt {q, q+8}, SAME bh
// (shared K/V working set in L2). 512 thr = 8 waves; wave w owns q-rows
// w*16..w*16+15. All waves walk the same 64-key chunk sequence; each chunk's
// K (64x64) and V^T (64x64) are staged cooperatively into LDS via
// global_load_lds (1 instr/thread each), double-buffered: STAGE(t+1) is
// issued before compute(t) so global latency hides under MFMA+softmax.
// LDS tiles have 128B rows -> XOR-swizzle byte^=((row&7)<<4) applied on BOTH
// sides (pre-swizzled global source, swizzled ds_read) per rule #21.
// ---------------------------------------------------------------------------
__global__ __launch_bounds__(512) void flash_mfma(
    const ushortt* __restrict__ Qr, const ushortt* __restrict__ Kr,
    const ushortt* __restrict__ Vr, ushortt* __restrict__ ctx) {
  const int id = blockIdx.x;
  const int qt = id >> 5;
  const int bh = id & 31;
  const int q0 = qt * 128;
  const int b = bh >> 4, h = bh & 15;
  const int tid = threadIdx.x;
  const int w = tid >> 6;
  const int lane = tid & 63;
  const int fr = lane & 15;
  const int quad = lane >> 4;

  __shared__ __align__(16) short Kb[2][4096];     // 2 x 8KB: [key][dim]
  __shared__ __align__(16) short Vb[2][4096];     // 2 x 8KB: [dim][key]
  __shared__ __align__(16) ushortt Ps[8][16][72]; // per-wave P tiles

  const size_t qkbase = (size_t)bh * SEQ * 64;
  const size_t vbase = (size_t)bh * 64 * SEQ;

  // Per-lane pre-swizzled stage source (bytes within an 8KB chunk).
  // LDS dest is linear (wave base + lane*16); involution lin^((lin>>7&7)<<4).
  const int lin = (w << 10) + ((lane & 63) << 4);
  const int swz = lin ^ (((lin >> 7) & 7) << 4);
  const char* ksrc = (const char*)(Kr + qkbase) + swz;
  const char* vsrc = (const char*)(Vr + vbase) + swz;
  short* kdst[2] = {&Kb[0][w * 512], &Kb[1][w * 512]};
  short* vdst[2] = {&Vb[0][w * 512], &Vb[1][w * 512]};

  // Q fragments: registers for the whole kernel
  frag8 aq[2];
#pragma unroll
  for (int hh = 0; hh < 2; ++hh)
    aq[hh] = *(const frag8*)(Qr + qkbase + (size_t)(q0 + w * 16 + fr) * 64 +
                             hh * 32 + quad * 8);

  float mr[4], lr[4];
  f32x4 od[4] = {};  // od[dtile][reg]; row = quad*4+reg, col = dt*16+fr
#pragma unroll
  for (int r = 0; r < 4; ++r) { mr[r] = -1e30f; lr[r] = 0.0f; }

  const int nt = 2 * qt + 2;

  // prologue: stage chunk 0 into buffer 0
  __builtin_amdgcn_global_load_lds(
      (const __attribute__((address_space(1))) void*)ksrc,
      (__attribute__((address_space(3))) void*)kdst[0], 16, 0, 0);
  __builtin_amdgcn_global_load_lds(
      (const __attribute__((address_space(1))) void*)vsrc,
      (__attribute__((address_space(3))) void*)vdst[0], 16, 0, 0);
  __syncthreads();

  for (int t = 0; t < nt; ++t) {
    const int c0 = t * 64;
    // issue next chunk's stage before compute (hidden under compute(t))
    if (t + 1 < nt) {
      const char* kn = ksrc + (size_t)(t + 1) * 8192;
      const char* vn = vsrc + (size_t)(t + 1) * 8192;
      __builtin_amdgcn_global_load_lds(
          (const __attribute__((address_space(1))) void*)kn,
          (__attribute__((address_space(3))) void*)kdst[(t + 1) & 1], 16, 0, 0);
      __builtin_amdgcn_global_load_lds(
          (const __attribute__((address_space(1))) void*)vn,
          (__attribute__((address_space(3))) void*)vdst[(t + 1) & 1], 16, 0, 0);
    }
    const char* kcur = (const char*)Kb[t & 1];
    const char* vcur = (const char*)Vb[t & 1];

    // wave active iff chunk intersects this wave's causal range
    if (c0 <= q0 + w * 16 + 15) {
      // ---- S = Q K^T (A=Q[m][d], B=K[n][d], from swizzled LDS) ----
      f32x4 sc[4] = {};
#pragma unroll
      for (int ni = 0; ni < 4; ++ni)
#pragma unroll
        for (int hh = 0; hh < 2; ++hh) {
          int kb = (((ni * 16 + fr) << 7) + (hh << 6) + (quad << 4)) ^
                   ((fr & 7) << 4);
          frag8 kf = *(const frag8*)(kcur + kb);
          sc[ni] = __builtin_amdgcn_mfma_f32_16x16x32_bf16(aq[hh], kf, sc[ni],
                                                           0, 0, 0);
        }

      // ---- causal mask (only when chunk straddles the diagonal) ----
      if (c0 + 63 > q0 + w * 16) {
        int rowb = q0 + w * 16 + quad * 4;
#pragma unroll
        for (int ni = 0; ni < 4; ++ni) {
          int col = c0 + ni * 16 + fr;
#pragma unroll
          for (int r = 0; r < 4; ++r)
            if (col > rowb + r) sc[ni][r] = -1e30f;
        }
      }

      // ---- online softmax per row (quad's 16 lanes hold the row) ----
#pragma unroll
      for (int r = 0; r < 4; ++r) {
        float cm = fmaxf(fmaxf(sc[0][r], sc[1][r]), fmaxf(sc[2][r], sc[3][r]));
        for (int off = 1; off < 16; off <<= 1)
          cm = fmaxf(cm, __shfl_xor(cm, off, 16));
        float mn = fmaxf(mr[r], cm);
        float corr = __expf(mr[r] - mn);
        mr[r] = mn;
        float ps = 0.0f;
#pragma unroll
        for (int ni = 0; ni < 4; ++ni) {
          float p = __expf(sc[ni][r] - mn);
          Ps[w][quad * 4 + r][ni * 16 + fr] = f2bu(p);
          ps += p;
        }
        for (int off = 1; off < 16; off <<= 1) ps += __shfl_xor(ps, off, 16);
        lr[r] = lr[r] * corr + ps;
#pragma unroll
        for (int dt = 0; dt < 4; ++dt) od[dt][r] *= corr;
      }
      // wave-local Ps rows: in-order wave + lgkmcnt => no barrier needed

      // ---- O += P V (A=P[m][key], B=V^T[d][key], from swizzled LDS) ----
      frag8 pf[2];
#pragma unroll
      for (int hh = 0; hh < 2; ++hh)
        pf[hh] = *(const frag8*)&Ps[w][fr][hh * 32 + quad * 8];
#pragma unroll
      for (int dt = 0; dt < 4; ++dt)
#pragma unroll
        for (int hh = 0; hh < 2; ++hh) {
          int vb_ = (((dt * 16 + fr) << 7) + (hh << 6) + (quad << 4)) ^
                    ((fr & 7) << 4);
          frag8 vf = *(const frag8*)(vcur + vb_);
          od[dt] = __builtin_amdgcn_mfma_f32_16x16x32_bf16(pf[hh], vf, od[dt],
                                                           0, 0, 0);
        }
    }
    // barrier: drains stage(t+1) (vmcnt) + all waves done reading buf[t&1]
    __syncthreads();
  }

  // ---- write ctx (B,S,DIM) bf16 ----
#pragma unroll
  for (int r = 0; r < 4; ++r) {
    float inv = 1.0f / lr[r];
    size_t row = (size_t)(b * SEQ + q0 + w * 16 + quad * 4 + r) * DIMSZ + h * 64;
#pragma unroll
    for (int dt = 0; dt < 4; ++dt)
      ctx[row + dt * 16 + fr] = f2bu(od[dt][r] * inv);
  }
}

// ---------------------------------------------------------------------------
// y = res + proj; out = scale * y / (||y||*D^-0.5 + eps). One block per row.
// DUAL=1 also writes bf16 copy (GEMM A operand).
// ---------------------------------------------------------------------------
template <int DUAL>
__global__ __launch_bounds__(256) void add_rmsnorm(
    const float* __restrict__ res, const float* __restrict__ proj,
    const float* __restrict__ scale, float* __restrict__ out,
    ushortt* __restrict__ out2) {
  const int row = blockIdx.x;
  const int tid = threadIdx.x;
  const size_t base = (size_t)row * DIMSZ;
  __shared__ float red[4];
  float y[4];
  float ss = 0.0f;
#pragma unroll
  for (int j = 0; j < 4; ++j) {
    int d = tid + j * 256;
    float yv = res[base + d] + proj[base + d];
    y[j] = yv;
    ss += yv * yv;
  }
  for (int off = 1; off < 64; off <<= 1) ss += __shfl_xor(ss, off, 64);
  if ((tid & 63) == 0) red[tid >> 6] = ss;
  __syncthreads();
  float tot = red[0] + red[1] + red[2] + red[3];
  float norm = sqrtf(tot) * 0.03125f;
  float inv = 1.0f / (norm + 1e-8f);
#pragma unroll
  for (int j = 0; j < 4; ++j) {
    int d = tid + j * 256;
    float v = scale[d] * y[j] * inv;
    out[base + d] = v;
    if (DUAL) out2[base + d] = f2bu(v);
  }
}

// ---------------------------------------------------------------------------
extern "C" void kernel_launch(void* const* d_in, const int* in_sizes, int n_in,
                              void* d_out, int out_size, void* d_ws, size_t ws_size,
                              hipStream_t stream) {
  const float* x          = (const float*)d_in[0];
  // d_in[1] = causal mask (bool) — structure hardcoded, unused
  const float* qkv_w      = (const float*)d_in[2];
  const float* attn_out_w = (const float*)d_in[3];
  const float* gate_w     = (const float*)d_in[4];
  const float* gate_b     = (const float*)d_in[5];
  const float* lin_w      = (const float*)d_in[6];
  const float* lin_b      = (const float*)d_in[7];
  const float* ff_out_w   = (const float*)d_in[8];
  const float* n1s        = (const float*)d_in[9];
  const float* n2s        = (const float*)d_in[10];
  float* out = (float*)d_out;

  const int M = NBATCH * SEQ;  // 4096
  char* ws = (char*)d_ws;
  char* dob = (char*)d_out;
  const size_t MB = 1 << 20;
  // ws layout (bytes), lifetime-disjoint; high-water 48 MB (< proven 50.3):
  ushortt* qkv_tmp = (ushortt*)(ws + 0);        // [0,24)  bf16, p1..rope
  ushortt* xb      = (ushortt*)(ws + 24 * MB);  // [24,32) bf16, p1 (pre-Qr)
  ushortt* qkv_wb  = (ushortt*)(ws + 32 * MB);  // [32,38) bf16, p1 (pre-Kr)
  ushortt* Qr      = (ushortt*)(ws + 24 * MB);  // [24,32) bf16, rope..attn
  ushortt* Kr      = (ushortt*)(ws + 32 * MB);  // [32,40) bf16, rope..attn
  ushortt* Vr      = (ushortt*)(ws + 40 * MB);  // [40,48) bf16, rope..attn
  ushortt* attn_wb = (ushortt*)(ws + 24 * MB);  // [24,26) bf16, p3 (Qr dead)
  float*   proj    = (float*)(ws + 0);          // [0,16)  fp32, p3..p4 (qkv dead)
  float*   x1      = (float*)(ws + 16 * MB);    // [16,32) fp32, p4..end
  ushortt* x1b     = (ushortt*)(ws + 32 * MB);  // [32,40) bf16, p4..end (Kr dead)
  float*   proj2   = (float*)(ws + 0);          // [0,16)  fp32, p5..end
  ushortt* gcb     = (ushortt*)(ws + 40 * MB);  // [40,42) bf16, p5 chunk (Vr dead)
  ushortt* lcb     = (ushortt*)(ws + 42 * MB);  // [42,44)
  ushortt* focb    = (ushortt*)(ws + 44 * MB);  // [44,46)
  // d_out doubles as scratch:
  ushortt* ctx  = (ushortt*)(dob + 0);          // [0,8)  bf16, p2..p3
  ushortt* ffc  = (ushortt*)(dob + 0);          // [0,8)  bf16, p5 chunk

  // p1: casts + qkv GEMM (bf16 out)
  cast_f2b<<<4194304 / 1024, 256, 0, stream>>>(x, xb, 4194304);
  cast_f2b<<<3145728 / 1024, 256, 0, stream>>>(qkv_w, qkv_wb, 3145728);
  gemm_mfma<1><<<dim3(3072 / 128, M / 128), 256, 0, stream>>>(
      xb, qkv_wb, qkv_tmp, nullptr, nullptr, M, 3072, DIMSZ, 0);
  // p2: RoPE prep + MFMA flash attention (LDS-staged, 512 blocks of 8 waves)
  rope_prep<<<dim3(SEQ / 64, NBATCH * NHEAD), 256, 0, stream>>>(
      qkv_tmp, Qr, Kr, Vr);
  flash_mfma<<<(SEQ / 128) * NBATCH * NHEAD, 512, 0, stream>>>(
      Qr, Kr, Vr, ctx);
  // p3: attn projection (fp32 out)
  cast_f2b<<<1048576 / 1024, 256, 0, stream>>>(attn_out_w, attn_wb, 1048576);
  gemm_mfma<0><<<dim3(DIMSZ / 128, M / 128), 256, 0, stream>>>(
      ctx, attn_wb, proj, nullptr, nullptr, M, DIMSZ, DIMSZ, 0);
  // p4: x1 = rmsnorm(x + proj), fp32 + bf16 copies
  add_rmsnorm<1><<<M, 256, 0, stream>>>(x, proj, n1s, x1, x1b);
  // p5: FF in 4 chunks of 1024; fused gate+lin, then ffout accumulates fp32
  for (int c = 0; c < 4; ++c) {
    cast_ff_chunk<<<3072, 256, 0, stream>>>(gate_w, lin_w, ff_out_w, c,
                                            gcb, lcb, focb);
    gemm_gatelin<<<dim3(1024 / 128, M / 128), 256, 0, stream>>>(
        x1b, gcb, lcb, ffc, gate_b + c * 1024, lin_b + c * 1024,
        M, 1024, DIMSZ);
    gemm_mfma<4><<<dim3(DIMSZ / 128, M / 128), 256, 0, stream>>>(
        ffc, focb, proj2, nullptr, nullptr, M, DIMSZ, 1024, c == 0 ? 1 : 0);
  }
  // p6: out = rmsnorm(x1 + proj2)
  add_rmsnorm<0><<<M, 256, 0, stream>>>(x1, proj2, n2s, out, nullptr);
}

// Round 5
// 607.492 us; speedup vs baseline: 1.4342x; 1.0125x over previous
//
#include <hip/hip_runtime.h>
#include <hip/hip_bf16.h>
#include <math.h>

#define DIMSZ 1024
#define NHEAD 16
#define HDIM 64
#define FFDIM 4096
#define SEQ 2048
#define NBATCH 2

typedef unsigned short ushortt;
typedef __attribute__((ext_vector_type(8))) short frag8;   // 8 bf16 (4 VGPR)
typedef __attribute__((ext_vector_type(4))) float f32x4;   // MFMA acc

// bf16 (stored as ushort) <-> fp32
__device__ __forceinline__ float u2f(ushortt u) {
  return __uint_as_float(((unsigned)u) << 16);
}
__device__ __forceinline__ ushortt f2bu(float f) {  // RNE
  unsigned x = __float_as_uint(f);
  return (ushortt)((x + 0x7FFFu + ((x >> 16) & 1u)) >> 16);
}

// ---------------------------------------------------------------------------
// fp32 -> bf16 cast, 4 elems/thread, n % 4 == 0
// ---------------------------------------------------------------------------
__global__ __launch_bounds__(256) void cast_f2b(
    const float* __restrict__ src, ushortt* __restrict__ dst, int n) {
  int i = (blockIdx.x * 256 + threadIdx.x) * 4;
  if (i >= n) return;
  float4 f = *(const float4*)(src + i);
  ushort4 u;
  u.x = f2bu(f.x); u.y = f2bu(f.y); u.z = f2bu(f.z); u.w = f2bu(f.w);
  *(ushort4*)(dst + i) = u;
}

// ---------------------------------------------------------------------------
// MFMA GEMM, double-buffered: STAGE(t+1) issued before compute(t), single
// barrier per K-step. EPI: 0 fp32 store | 1 bf16 store
// ---------------------------------------------------------------------------
template <int EPI>
__global__ __launch_bounds__(256) void gemm_mfma(
    const ushortt* __restrict__ A, const ushortt* __restrict__ W,
    void* __restrict__ Cv, int M, int N, int K) {
  __shared__ __align__(16) short As[2][128 * 32];
  __shared__ __align__(16) short Bs[2][128 * 32];
  const int tid = threadIdx.x;
  const int wave = tid >> 6;
  const int lane = tid & 63;
  const int bm = blockIdx.y * 128;
  const int bn = blockIdx.x * 128;
  const int wm = (wave >> 1) * 64;
  const int wn = (wave & 1) * 64;

  f32x4 acc[4][4] = {};

  const int sr = lane >> 2;
  const int sc = (lane & 3) * 8;
  const ushortt* pa0 = A + (size_t)(bm + wave * 16 + sr) * K + sc;
  const ushortt* pa1 = pa0 + (size_t)64 * K;
  const ushortt* pb0 = W + (size_t)(bn + wave * 16 + sr) * K + sc;
  const ushortt* pb1 = pb0 + (size_t)64 * K;
  const int lo0 = (wave * 16) * 32;
  const int lo1 = (64 + wave * 16) * 32;

  const int fr = lane & 15;
  const int fq = (lane >> 4) * 8;
  const int nt = K >> 5;

  auto stage = [&](int t, int buf) {
    const int ko = t * 32;
    short* ab = &As[0][0] + buf * 4096;
    short* bb = &Bs[0][0] + buf * 4096;
    __builtin_amdgcn_global_load_lds(
        (const __attribute__((address_space(1))) void*)(pa0 + ko),
        (__attribute__((address_space(3))) void*)(ab + lo0), 16, 0, 0);
    __builtin_amdgcn_global_load_lds(
        (const __attribute__((address_space(1))) void*)(pa1 + ko),
        (__attribute__((address_space(3))) void*)(ab + lo1), 16, 0, 0);
    __builtin_amdgcn_global_load_lds(
        (const __attribute__((address_space(1))) void*)(pb0 + ko),
        (__attribute__((address_space(3))) void*)(bb + lo0), 16, 0, 0);
    __builtin_amdgcn_global_load_lds(
        (const __attribute__((address_space(1))) void*)(pb1 + ko),
        (__attribute__((address_space(3))) void*)(bb + lo1), 16, 0, 0);
  };

  stage(0, 0);
  __syncthreads();

  for (int t = 0; t < nt; ++t) {
    if (t + 1 < nt) stage(t + 1, (t + 1) & 1);
    const short* as = &As[0][0] + (t & 1) * 4096;
    const short* bs = &Bs[0][0] + (t & 1) * 4096;

    frag8 af[4], bf[4];
#pragma unroll
    for (int mi = 0; mi < 4; ++mi)
      af[mi] = *(const frag8*)&as[(wm + mi * 16 + fr) * 32 + fq];
#pragma unroll
    for (int ni = 0; ni < 4; ++ni)
      bf[ni] = *(const frag8*)&bs[(wn + ni * 16 + fr) * 32 + fq];
#pragma unroll
    for (int mi = 0; mi < 4; ++mi)
#pragma unroll
      for (int ni = 0; ni < 4; ++ni)
        acc[mi][ni] = __builtin_amdgcn_mfma_f32_16x16x32_bf16(
            af[mi], bf[ni], acc[mi][ni], 0, 0, 0);
    __syncthreads();
  }

  const int er = (lane >> 4) * 4;
  const int ec = lane & 15;
#pragma unroll
  for (int mi = 0; mi < 4; ++mi)
#pragma unroll
    for (int ni = 0; ni < 4; ++ni)
#pragma unroll
      for (int r = 0; r < 4; ++r) {
        int m = bm + wm + mi * 16 + er + r;
        int n = bn + wn + ni * 16 + ec;
        size_t o = (size_t)m * N + n;
        float v = acc[mi][ni][r];
        if (EPI == 0) {
          ((float*)Cv)[o] = v;
        } else {
          ((ushortt*)Cv)[o] = f2bu(v);
        }
      }
}

// ---------------------------------------------------------------------------
// Fused gate+lin GEMM: one staged A tile feeds TWO B tiles, 32 MFMA/K-step,
// dual accumulators. Epilogue: out = sigmoid(g+gbias)*(l+lbias) -> bf16.
// Launched with N-chunk 2048 -> 512 blocks = 2/CU (cross-block latency hide).
// ---------------------------------------------------------------------------
__global__ __launch_bounds__(256) void gemm_gatelin(
    const ushortt* __restrict__ A, const ushortt* __restrict__ Wg,
    const ushortt* __restrict__ Wl, ushortt* __restrict__ Cv,
    const float* __restrict__ gbias, const float* __restrict__ lbias,
    int M, int N, int K) {
  __shared__ __align__(16) short As[2][128 * 32];
  __shared__ __align__(16) short Gs[2][128 * 32];
  __shared__ __align__(16) short Ls[2][128 * 32];
  const int tid = threadIdx.x;
  const int wave = tid >> 6;
  const int lane = tid & 63;
  const int bm = blockIdx.y * 128;
  const int bn = blockIdx.x * 128;
  const int wm = (wave >> 1) * 64;
  const int wn = (wave & 1) * 64;

  f32x4 accg[4][4] = {};
  f32x4 accl[4][4] = {};

  const int sr = lane >> 2;
  const int sc = (lane & 3) * 8;
  const ushortt* pa0 = A + (size_t)(bm + wave * 16 + sr) * K + sc;
  const ushortt* pa1 = pa0 + (size_t)64 * K;
  const ushortt* pg0 = Wg + (size_t)(bn + wave * 16 + sr) * K + sc;
  const ushortt* pg1 = pg0 + (size_t)64 * K;
  const ushortt* pl0 = Wl + (size_t)(bn + wave * 16 + sr) * K + sc;
  const ushortt* pl1 = pl0 + (size_t)64 * K;
  const int lo0 = (wave * 16) * 32;
  const int lo1 = (64 + wave * 16) * 32;

  const int fr = lane & 15;
  const int fq = (lane >> 4) * 8;
  const int nt = K >> 5;

  auto stage = [&](int t, int buf) {
    const int ko = t * 32;
    short* ab = &As[0][0] + buf * 4096;
    short* gb = &Gs[0][0] + buf * 4096;
    short* lb = &Ls[0][0] + buf * 4096;
    __builtin_amdgcn_global_load_lds(
        (const __attribute__((address_space(1))) void*)(pa0 + ko),
        (__attribute__((address_space(3))) void*)(ab + lo0), 16, 0, 0);
    __builtin_amdgcn_global_load_lds(
        (const __attribute__((address_space(1))) void*)(pa1 + ko),
        (__attribute__((address_space(3))) void*)(ab + lo1), 16, 0, 0);
    __builtin_amdgcn_global_load_lds(
        (const __attribute__((address_space(1))) void*)(pg0 + ko),
        (__attribute__((address_space(3))) void*)(gb + lo0), 16, 0, 0);
    __builtin_amdgcn_global_load_lds(
        (const __attribute__((address_space(1))) void*)(pg1 + ko),
        (__attribute__((address_space(3))) void*)(gb + lo1), 16, 0, 0);
    __builtin_amdgcn_global_load_lds(
        (const __attribute__((address_space(1))) void*)(pl0 + ko),
        (__attribute__((address_space(3))) void*)(lb + lo0), 16, 0, 0);
    __builtin_amdgcn_global_load_lds(
        (const __attribute__((address_space(1))) void*)(pl1 + ko),
        (__attribute__((address_space(3))) void*)(lb + lo1), 16, 0, 0);
  };

  stage(0, 0);
  __syncthreads();

  for (int t = 0; t < nt; ++t) {
    if (t + 1 < nt) stage(t + 1, (t + 1) & 1);
    const short* as = &As[0][0] + (t & 1) * 4096;
    const short* gs = &Gs[0][0] + (t & 1) * 4096;
    const short* ls = &Ls[0][0] + (t & 1) * 4096;

    frag8 af[4], gf[4], lf[4];
#pragma unroll
    for (int mi = 0; mi < 4; ++mi)
      af[mi] = *(const frag8*)&as[(wm + mi * 16 + fr) * 32 + fq];
#pragma unroll
    for (int ni = 0; ni < 4; ++ni) {
      gf[ni] = *(const frag8*)&gs[(wn + ni * 16 + fr) * 32 + fq];
      lf[ni] = *(const frag8*)&ls[(wn + ni * 16 + fr) * 32 + fq];
    }
#pragma unroll
    for (int mi = 0; mi < 4; ++mi)
#pragma unroll
      for (int ni = 0; ni < 4; ++ni) {
        accg[mi][ni] = __builtin_amdgcn_mfma_f32_16x16x32_bf16(
            af[mi], gf[ni], accg[mi][ni], 0, 0, 0);
        accl[mi][ni] = __builtin_amdgcn_mfma_f32_16x16x32_bf16(
            af[mi], lf[ni], accl[mi][ni], 0, 0, 0);
      }
    __syncthreads();
  }

  const int er = (lane >> 4) * 4;
  const int ec = lane & 15;
#pragma unroll
  for (int mi = 0; mi < 4; ++mi)
#pragma unroll
    for (int ni = 0; ni < 4; ++ni)
#pragma unroll
      for (int r = 0; r < 4; ++r) {
        int m = bm + wm + mi * 16 + er + r;
        int n = bn + wn + ni * 16 + ec;
        size_t o = (size_t)m * N + n;
        float g = accg[mi][ni][r] + gbias[n];
        float l = accl[mi][ni][r] + lbias[n];
        float sig = 1.0f / (1.0f + __expf(-g));
        ((ushortt*)Cv)[o] = f2bu(sig * l);
      }
}

// ---------------------------------------------------------------------------
// FF-out GEMM with on-the-fly fp32->bf16 B staging (no pre-cast pass).
// A = ffc bf16 [M][lda=2048]; B = ff_out_w fp32 [1024][FFDIM], k-offset koff.
// B staging: per thread 2x (2 float4 loads from one row) -> f2bu -> one
// 16B LDS write at linear stride-16 (conflict-free). Loads for t+1 issued
// before compute(t); ds_write after compute (issue-early/write-late, T14);
// single barrier per K-step (disjoint buffer parity).
// C = proj2 fp32, accumulate across the 2 K-chunks (first ? = : +=).
// ---------------------------------------------------------------------------
__global__ __launch_bounds__(256) void gemm_ffout(
    const ushortt* __restrict__ A, const float* __restrict__ Bw,
    float* __restrict__ C, int lda, int koff, int first) {
  __shared__ __align__(16) short As[2][128 * 32];
  __shared__ __align__(16) short Bs[2][128 * 32];
  const int tid = threadIdx.x;
  const int wave = tid >> 6;
  const int lane = tid & 63;
  const int bm = blockIdx.y * 128;
  const int bn = blockIdx.x * 128;
  const int wm = (wave >> 1) * 64;
  const int wn = (wave & 1) * 64;

  f32x4 acc[4][4] = {};

  const int sr = lane >> 2;
  const int sc = (lane & 3) * 8;
  const ushortt* pa0 = A + (size_t)(bm + wave * 16 + sr) * lda + sc;
  const ushortt* pa1 = pa0 + (size_t)64 * lda;
  const int lo0 = (wave * 16) * 32;
  const int lo1 = (64 + wave * 16) * 32;

  // B reg-stage mapping: thread -> row br (0..63 / 64..127), k-part kc
  const int br = tid >> 2;         // 0..63
  const int kc = (tid & 3) * 8;    // 0,8,16,24 within the 32-k step
  const float* pb0 = Bw + (size_t)(bn + br) * FFDIM + koff + kc;
  const float* pb1 = pb0 + (size_t)64 * FFDIM;

  const int fr = lane & 15;
  const int fq = (lane >> 4) * 8;
  const int nt = 2048 >> 5;  // 64

  float4 f0, f1, f2, f3;
  auto bload = [&](int t) {
    const float* p0 = pb0 + t * 32;
    const float* p1 = pb1 + t * 32;
    f0 = *(const float4*)p0; f1 = *(const float4*)(p0 + 4);
    f2 = *(const float4*)p1; f3 = *(const float4*)(p1 + 4);
  };
  auto pk = [&](float4 a, float4 b) {
    frag8 v;
    v[0] = (short)f2bu(a.x); v[1] = (short)f2bu(a.y);
    v[2] = (short)f2bu(a.z); v[3] = (short)f2bu(a.w);
    v[4] = (short)f2bu(b.x); v[5] = (short)f2bu(b.y);
    v[6] = (short)f2bu(b.z); v[7] = (short)f2bu(b.w);
    return v;
  };
  auto bwrite = [&](int buf) {
    // rows 0..63 at shorts [tid*8], rows 64..127 at [2048 + tid*8]
    *(frag8*)&Bs[buf][tid * 8] = pk(f0, f1);
    *(frag8*)&Bs[buf][2048 + tid * 8] = pk(f2, f3);
  };
  auto astage = [&](int t, int buf) {
    const int ko = t * 32;
    short* ab = &As[0][0] + buf * 4096;
    __builtin_amdgcn_global_load_lds(
        (const __attribute__((address_space(1))) void*)(pa0 + ko),
        (__attribute__((address_space(3))) void*)(ab + lo0), 16, 0, 0);
    __builtin_amdgcn_global_load_lds(
        (const __attribute__((address_space(1))) void*)(pa1 + ko),
        (__attribute__((address_space(3))) void*)(ab + lo1), 16, 0, 0);
  };

  astage(0, 0);
  bload(0);
  bwrite(0);  // compiler inserts vmcnt for f regs
  __syncthreads();

  for (int t = 0; t < nt; ++t) {
    if (t + 1 < nt) {
      astage(t + 1, (t + 1) & 1);
      bload(t + 1);  // HBM/L2 latency hides under compute(t)
    }
    const short* as = &As[0][0] + (t & 1) * 4096;
    const short* bs = &Bs[0][0] + (t & 1) * 4096;

    frag8 af[4], bf[4];
#pragma unroll
    for (int mi = 0; mi < 4; ++mi)
      af[mi] = *(const frag8*)&as[(wm + mi * 16 + fr) * 32 + fq];
#pragma unroll
    for (int ni = 0; ni < 4; ++ni)
      bf[ni] = *(const frag8*)&bs[(wn + ni * 16 + fr) * 32 + fq];
#pragma unroll
    for (int mi = 0; mi < 4; ++mi)
#pragma unroll
      for (int ni = 0; ni < 4; ++ni)
        acc[mi][ni] = __builtin_amdgcn_mfma_f32_16x16x32_bf16(
            af[mi], bf[ni], acc[mi][ni], 0, 0, 0);
    if (t + 1 < nt) bwrite((t + 1) & 1);  // write-late into opposite buffer
    __syncthreads();
  }

  const int er = (lane >> 4) * 4;
  const int ec = lane & 15;
#pragma unroll
  for (int mi = 0; mi < 4; ++mi)
#pragma unroll
    for (int ni = 0; ni < 4; ++ni)
#pragma unroll
      for (int r = 0; r < 4; ++r) {
        int m = bm + wm + mi * 16 + er + r;
        int n = bn + wn + ni * 16 + ec;
        size_t o = (size_t)m * 1024 + n;
        float v = acc[mi][ni][r];
        C[o] = first ? v : C[o] + v;
      }
}

// ---------------------------------------------------------------------------
// RoPE prep: qkv (B,S,3,H,D) bf16 -> Qr,Kr [bh][S][64] (Q scaled 1/8),
// Vr chunk-blocked [bh][S/64][64 d][64 key] (transposed per 64-seq chunk).
// ---------------------------------------------------------------------------
__global__ __launch_bounds__(256) void rope_prep(
    const ushortt* __restrict__ qkv, ushortt* __restrict__ Qr,
    ushortt* __restrict__ Kr, ushortt* __restrict__ Vr) {
  const int s0 = blockIdx.x * 64;
  const int bh = blockIdx.y;
  const int b = bh >> 4, h = bh & 15;
  const int tid = threadIdx.x;
  __shared__ float ifr_s[32];
  __shared__ ushortt vt[64][72];
  if (tid < 32) ifr_s[tid] = __powf(10000.0f, -(float)tid * (1.0f / 32.0f));
  __syncthreads();
  const size_t qbase = (size_t)bh * SEQ * 64;

#pragma unroll
  for (int i = 0; i < 8; ++i) {
    int p = i * 256 + tid;
    int r = p >> 5, d = p & 31;
    size_t src = ((size_t)(b * SEQ + s0 + r)) * (3 * DIMSZ) + h * 64 + d;
    float q1 = u2f(qkv[src]), q2 = u2f(qkv[src + 32]);
    float k1 = u2f(qkv[src + DIMSZ]), k2 = u2f(qkv[src + DIMSZ + 32]);
    float ang = (float)(s0 + r) * ifr_s[d];
    float sn, cs;
    __sincosf(ang, &sn, &cs);
    size_t dst = qbase + (size_t)(s0 + r) * 64 + d;
    Qr[dst]      = f2bu((q1 * cs - q2 * sn) * 0.125f);
    Qr[dst + 32] = f2bu((q1 * sn + q2 * cs) * 0.125f);
    Kr[dst]      = f2bu(k1 * cs - k2 * sn);
    Kr[dst + 32] = f2bu(k1 * sn + k2 * cs);
  }

#pragma unroll
  for (int i = 0; i < 2; ++i) {
    int e = (i * 256 + tid) * 8;
    int r = e >> 6, d0 = e & 63;
    size_t src = ((size_t)(b * SEQ + s0 + r)) * (3 * DIMSZ) + 2 * DIMSZ + h * 64 + d0;
    *(ushort4*)&vt[r][d0]     = *(const ushort4*)(qkv + src);
    *(ushort4*)&vt[r][d0 + 4] = *(const ushort4*)(qkv + src + 4);
  }
  __syncthreads();
  {
    int d = tid >> 2;
    int sc0 = (tid & 3) * 16;
    size_t dst = (size_t)bh * 64 * SEQ + (size_t)blockIdx.x * 4096 +
                 (size_t)d * 64 + sc0;
    ushortt tmp[16];
#pragma unroll
    for (int j = 0; j < 16; ++j) tmp[j] = vt[sc0 + j][d];
    *(ushort4*)(Vr + dst)      = *(ushort4*)&tmp[0];
    *(ushort4*)(Vr + dst + 4)  = *(ushort4*)&tmp[4];
    *(ushort4*)(Vr + dst + 8)  = *(ushort4*)&tmp[8];
    *(ushort4*)(Vr + dst + 12) = *(ushort4*)&tmp[12];
  }
}

// ---------------------------------------------------------------------------
// MFMA flash attention, LDS-staged K/V with double-buffered prefetch.
// 1D grid of 512 blocks. Decode pairs qt q with 15-q across the two
// 256-id halves: CU hosting ids {c, c+256} gets qt {q, 15-q} -> per-CU cost
// 2(q+1)+2(16-q) = 34 CONSTANT (was 4q+20, worst/avg 1.41), same bh on both
// (shared K/V in L2). 8 waves; wave w owns q-rows w*16..+15; K/V chunks
// staged via global_load_lds, double-buffered, STAGE(t+1) before compute(t).
// XOR-swizzle byte^=((row&7)<<4) on both sides (rule #21).
// ---------------------------------------------------------------------------
__global__ __launch_bounds__(512) void flash_mfma(
    const ushortt* __restrict__ Qr, const ushortt* __restrict__ Kr,
    const ushortt* __restrict__ Vr, ushortt* __restrict__ ctx) {
  const int id = blockIdx.x;
  const int r5 = id & 255;
  const int qt0 = r5 >> 5;
  const int qt = (id & 256) ? (15 - qt0) : qt0;   // balanced pairing
  const int bh = r5 & 31;
  const int q0 = qt * 128;
  const int b = bh >> 4, h = bh & 15;
  const int tid = threadIdx.x;
  const int w = tid >> 6;
  const int lane = tid & 63;
  const int fr = lane & 15;
  const int quad = lane >> 4;

  __shared__ __align__(16) short Kb[2][4096];     // 2 x 8KB: [key][dim]
  __shared__ __align__(16) short Vb[2][4096];     // 2 x 8KB: [dim][key]
  __shared__ __align__(16) ushortt Ps[8][16][72]; // per-wave P tiles

  const size_t qkbase = (size_t)bh * SEQ * 64;
  const size_t vbase = (size_t)bh * 64 * SEQ;

  const int lin = (w << 10) + ((lane & 63) << 4);
  const int swz = lin ^ (((lin >> 7) & 7) << 4);
  const char* ksrc = (const char*)(Kr + qkbase) + swz;
  const char* vsrc = (const char*)(Vr + vbase) + swz;
  short* kdst[2] = {&Kb[0][w * 512], &Kb[1][w * 512]};
  short* vdst[2] = {&Vb[0][w * 512], &Vb[1][w * 512]};

  frag8 aq[2];
#pragma unroll
  for (int hh = 0; hh < 2; ++hh)
    aq[hh] = *(const frag8*)(Qr + qkbase + (size_t)(q0 + w * 16 + fr) * 64 +
                             hh * 32 + quad * 8);

  float mr[4], lr[4];
  f32x4 od[4] = {};
#pragma unroll
  for (int r = 0; r < 4; ++r) { mr[r] = -1e30f; lr[r] = 0.0f; }

  const int nt = 2 * qt + 2;

  __builtin_amdgcn_global_load_lds(
      (const __attribute__((address_space(1))) void*)ksrc,
      (__attribute__((address_space(3))) void*)kdst[0], 16, 0, 0);
  __builtin_amdgcn_global_load_lds(
      (const __attribute__((address_space(1))) void*)vsrc,
      (__attribute__((address_space(3))) void*)vdst[0], 16, 0, 0);
  __syncthreads();

  for (int t = 0; t < nt; ++t) {
    const int c0 = t * 64;
    if (t + 1 < nt) {
      const char* kn = ksrc + (size_t)(t + 1) * 8192;
      const char* vn = vsrc + (size_t)(t + 1) * 8192;
      __builtin_amdgcn_global_load_lds(
          (const __attribute__((address_space(1))) void*)kn,
          (__attribute__((address_space(3))) void*)kdst[(t + 1) & 1], 16, 0, 0);
      __builtin_amdgcn_global_load_lds(
          (const __attribute__((address_space(1))) void*)vn,
          (__attribute__((address_space(3))) void*)vdst[(t + 1) & 1], 16, 0, 0);
    }
    const char* kcur = (const char*)Kb[t & 1];
    const char* vcur = (const char*)Vb[t & 1];

    if (c0 <= q0 + w * 16 + 15) {
      f32x4 sc[4] = {};
#pragma unroll
      for (int ni = 0; ni < 4; ++ni)
#pragma unroll
        for (int hh = 0; hh < 2; ++hh) {
          int kb = (((ni * 16 + fr) << 7) + (hh << 6) + (quad << 4)) ^
                   ((fr & 7) << 4);
          frag8 kf = *(const frag8*)(kcur + kb);
          sc[ni] = __builtin_amdgcn_mfma_f32_16x16x32_bf16(aq[hh], kf, sc[ni],
                                                           0, 0, 0);
        }

      if (c0 + 63 > q0 + w * 16) {
        int rowb = q0 + w * 16 + quad * 4;
#pragma unroll
        for (int ni = 0; ni < 4; ++ni) {
          int col = c0 + ni * 16 + fr;
#pragma unroll
          for (int r = 0; r < 4; ++r)
            if (col > rowb + r) sc[ni][r] = -1e30f;
        }
      }

#pragma unroll
      for (int r = 0; r < 4; ++r) {
        float cm = fmaxf(fmaxf(sc[0][r], sc[1][r]), fmaxf(sc[2][r], sc[3][r]));
        for (int off = 1; off < 16; off <<= 1)
          cm = fmaxf(cm, __shfl_xor(cm, off, 16));
        float mn = fmaxf(mr[r], cm);
        float corr = __expf(mr[r] - mn);
        mr[r] = mn;
        float ps = 0.0f;
#pragma unroll
        for (int ni = 0; ni < 4; ++ni) {
          float p = __expf(sc[ni][r] - mn);
          Ps[w][quad * 4 + r][ni * 16 + fr] = f2bu(p);
          ps += p;
        }
        for (int off = 1; off < 16; off <<= 1) ps += __shfl_xor(ps, off, 16);
        lr[r] = lr[r] * corr + ps;
#pragma unroll
        for (int dt = 0; dt < 4; ++dt) od[dt][r] *= corr;
      }

      frag8 pf[2];
#pragma unroll
      for (int hh = 0; hh < 2; ++hh)
        pf[hh] = *(const frag8*)&Ps[w][fr][hh * 32 + quad * 8];
#pragma unroll
      for (int dt = 0; dt < 4; ++dt)
#pragma unroll
        for (int hh = 0; hh < 2; ++hh) {
          int vb_ = (((dt * 16 + fr) << 7) + (hh << 6) + (quad << 4)) ^
                    ((fr & 7) << 4);
          frag8 vf = *(const frag8*)(vcur + vb_);
          od[dt] = __builtin_amdgcn_mfma_f32_16x16x32_bf16(pf[hh], vf, od[dt],
                                                           0, 0, 0);
        }
    }
    __syncthreads();
  }

#pragma unroll
  for (int r = 0; r < 4; ++r) {
    float inv = 1.0f / lr[r];
    size_t row = (size_t)(b * SEQ + q0 + w * 16 + quad * 4 + r) * DIMSZ + h * 64;
#pragma unroll
    for (int dt = 0; dt < 4; ++dt)
      ctx[row + dt * 16 + fr] = f2bu(od[dt][r] * inv);
  }
}

// ---------------------------------------------------------------------------
// y = res + proj; out = scale * y / (||y||*D^-0.5 + eps). One block per row.
// DUAL=1 also writes bf16 copy (GEMM A operand).
// ---------------------------------------------------------------------------
template <int DUAL>
__global__ __launch_bounds__(256) void add_rmsnorm(
    const float* __restrict__ res, const float* __restrict__ proj,
    const float* __restrict__ scale, float* __restrict__ out,
    ushortt* __restrict__ out2) {
  const int row = blockIdx.x;
  const int tid = threadIdx.x;
  const size_t base = (size_t)row * DIMSZ;
  __shared__ float red[4];
  float y[4];
  float ss = 0.0f;
#pragma unroll
  for (int j = 0; j < 4; ++j) {
    int d = tid + j * 256;
    float yv = res[base + d] + proj[base + d];
    y[j] = yv;
    ss += yv * yv;
  }
  for (int off = 1; off < 64; off <<= 1) ss += __shfl_xor(ss, off, 64);
  if ((tid & 63) == 0) red[tid >> 6] = ss;
  __syncthreads();
  float tot = red[0] + red[1] + red[2] + red[3];
  float norm = sqrtf(tot) * 0.03125f;
  float inv = 1.0f / (norm + 1e-8f);
#pragma unroll
  for (int j = 0; j < 4; ++j) {
    int d = tid + j * 256;
    float v = scale[d] * y[j] * inv;
    out[base + d] = v;
    if (DUAL) out2[base + d] = f2bu(v);
  }
}

// ---------------------------------------------------------------------------
extern "C" void kernel_launch(void* const* d_in, const int* in_sizes, int n_in,
                              void* d_out, int out_size, void* d_ws, size_t ws_size,
                              hipStream_t stream) {
  const float* x          = (const float*)d_in[0];
  // d_in[1] = causal mask (bool) — structure hardcoded, unused
  const float* qkv_w      = (const float*)d_in[2];
  const float* attn_out_w = (const float*)d_in[3];
  const float* gate_w     = (const float*)d_in[4];
  const float* gate_b     = (const float*)d_in[5];
  const float* lin_w      = (const float*)d_in[6];
  const float* lin_b      = (const float*)d_in[7];
  const float* ff_out_w   = (const float*)d_in[8];
  const float* n1s        = (const float*)d_in[9];
  const float* n2s        = (const float*)d_in[10];
  float* out = (float*)d_out;

  const int M = NBATCH * SEQ;  // 4096
  char* ws = (char*)d_ws;
  char* dob = (char*)d_out;
  const size_t MB = 1 << 20;
  // ws layout (bytes), lifetime-disjoint; high-water 48 MB (< proven 50.3):
  ushortt* qkv_tmp = (ushortt*)(ws + 0);        // [0,24)  bf16, p1..rope
  ushortt* xb      = (ushortt*)(ws + 24 * MB);  // [24,32) bf16, p1 (pre-Qr)
  ushortt* qkv_wb  = (ushortt*)(ws + 32 * MB);  // [32,38) bf16, p1 (pre-Kr)
  ushortt* Qr      = (ushortt*)(ws + 24 * MB);  // [24,32) bf16, rope..attn
  ushortt* Kr      = (ushortt*)(ws + 32 * MB);  // [32,40) bf16, rope..attn
  ushortt* Vr      = (ushortt*)(ws + 40 * MB);  // [40,48) bf16, rope..attn
  ushortt* attn_wb = (ushortt*)(ws + 24 * MB);  // [24,26) bf16, p3 (Qr dead)
  float*   proj    = (float*)(ws + 0);          // [0,16)  fp32, p3..p4 (qkv dead)
  float*   x1      = (float*)(ws + 16 * MB);    // [16,32) fp32, p4..end
  ushortt* x1b     = (ushortt*)(ws + 32 * MB);  // [32,40) bf16, p4..end (Kr dead)
  float*   proj2   = (float*)(ws + 0);          // [0,16)  fp32, p5..end (proj dead)
  ushortt* gcb     = (ushortt*)(ws + 40 * MB);  // [40,44) bf16, p5 chunk (Vr dead)
  ushortt* lcb     = (ushortt*)(ws + 44 * MB);  // [44,48)
  // d_out doubles as scratch:
  ushortt* ctx  = (ushortt*)(dob + 0);          // [0,8)  bf16, p2..p3
  ushortt* ffc  = (ushortt*)(dob + 0);          // [0,16) bf16, p5 chunk (ctx dead)

  // p1: casts + qkv GEMM (bf16 out)
  cast_f2b<<<4194304 / 1024, 256, 0, stream>>>(x, xb, 4194304);
  cast_f2b<<<3145728 / 1024, 256, 0, stream>>>(qkv_w, qkv_wb, 3145728);
  gemm_mfma<1><<<dim3(3072 / 128, M / 128), 256, 0, stream>>>(
      xb, qkv_wb, qkv_tmp, M, 3072, DIMSZ);
  // p2: RoPE prep + MFMA flash attention (balanced 1D grid)
  rope_prep<<<dim3(SEQ / 64, NBATCH * NHEAD), 256, 0, stream>>>(
      qkv_tmp, Qr, Kr, Vr);
  flash_mfma<<<(SEQ / 128) * NBATCH * NHEAD, 512, 0, stream>>>(
      Qr, Kr, Vr, ctx);
  // p3: attn projection (fp32 out)
  cast_f2b<<<1048576 / 1024, 256, 0, stream>>>(attn_out_w, attn_wb, 1048576);
  gemm_mfma<0><<<dim3(DIMSZ / 128, M / 128), 256, 0, stream>>>(
      ctx, attn_wb, proj, M, DIMSZ, DIMSZ);
  // p4: x1 = rmsnorm(x + proj), fp32 + bf16 copies
  add_rmsnorm<1><<<M, 256, 0, stream>>>(x, proj, n1s, x1, x1b);
  // p5: FF in 2 chunks of 2048: cast gate/lin (contiguous rows), fused
  // gatelin (512 blocks = 2/CU), ffout with on-the-fly fp32 B (no focb).
  for (int c = 0; c < 2; ++c) {
    cast_f2b<<<2048, 256, 0, stream>>>(
        gate_w + (size_t)c * 2097152, gcb, 2097152);
    cast_f2b<<<2048, 256, 0, stream>>>(
        lin_w + (size_t)c * 2097152, lcb, 2097152);
    gemm_gatelin<<<dim3(2048 / 128, M / 128), 256, 0, stream>>>(
        x1b, gcb, lcb, ffc, gate_b + c * 2048, lin_b + c * 2048,
        M, 2048, DIMSZ);
    gemm_ffout<<<dim3(1024 / 128, M / 128), 256, 0, stream>>>(
        ffc, ff_out_w, proj2, 2048, c * 2048, c == 0 ? 1 : 0);
  }
  // p6: out = rmsnorm(x1 + proj2)
  add_rmsnorm<0><<<M, 256, 0, stream>>>(x1, proj2, n2s, out, nullptr);
}

// Round 6
// 582.868 us; speedup vs baseline: 1.4948x; 1.0422x over previous
//
#include <hip/hip_runtime.h>
#include <hip/hip_bf16.h>
#include <math.h>

#define DIMSZ 1024
#define NHEAD 16
#define HDIM 64
#define FFDIM 4096
#define SEQ 2048
#define NBATCH 2

typedef unsigned short ushortt;
typedef __attribute__((ext_vector_type(8))) short frag8;   // 8 bf16 (4 VGPR)
typedef __attribute__((ext_vector_type(4))) float f32x4;   // MFMA acc

// bf16 (stored as ushort) <-> fp32
__device__ __forceinline__ float u2f(ushortt u) {
  return __uint_as_float(((unsigned)u) << 16);
}
__device__ __forceinline__ ushortt f2bu(float f) {  // RNE
  unsigned x = __float_as_uint(f);
  return (ushortt)((x + 0x7FFFu + ((x >> 16) & 1u)) >> 16);
}

// XCD-grouping block decode for 1D grids of NX x 32 tiles (M/128 == 32).
// id%8 = XCD (dispatch round-robin); each XCD owns 4 contiguous y-panels ->
// A-panel working set stays in that XCD's L2; blocks sharing a B panel are
// co-resident on the same XCD. Bijective: id <-> (bx, by).
__device__ __forceinline__ void xcd_decode(int id, int& bx, int& by) {
  const int xcd = id & 7;
  const int s = id >> 3;
  by = xcd * 4 + (s & 3);
  bx = s >> 2;
}

// ---------------------------------------------------------------------------
// fp32 -> bf16 cast, 4 elems/thread, n % 4 == 0
// ---------------------------------------------------------------------------
__global__ __launch_bounds__(256) void cast_f2b(
    const float* __restrict__ src, ushortt* __restrict__ dst, int n) {
  int i = (blockIdx.x * 256 + threadIdx.x) * 4;
  if (i >= n) return;
  float4 f = *(const float4*)(src + i);
  ushort4 u;
  u.x = f2bu(f.x); u.y = f2bu(f.y); u.z = f2bu(f.z); u.w = f2bu(f.w);
  *(ushort4*)(dst + i) = u;
}

// ---------------------------------------------------------------------------
// MFMA GEMM, double-buffered: STAGE(t+1) issued before compute(t), single
// barrier per K-step. 1D grid with xcd_decode. EPI: 0 fp32 | 1 bf16 store
// ---------------------------------------------------------------------------
template <int EPI>
__global__ __launch_bounds__(256) void gemm_mfma(
    const ushortt* __restrict__ A, const ushortt* __restrict__ W,
    void* __restrict__ Cv, int M, int N, int K) {
  __shared__ __align__(16) short As[2][128 * 32];
  __shared__ __align__(16) short Bs[2][128 * 32];
  const int tid = threadIdx.x;
  const int wave = tid >> 6;
  const int lane = tid & 63;
  int bx, by;
  xcd_decode(blockIdx.x, bx, by);
  const int bm = by * 128;
  const int bn = bx * 128;
  const int wm = (wave >> 1) * 64;
  const int wn = (wave & 1) * 64;

  f32x4 acc[4][4] = {};

  const int sr = lane >> 2;
  const int sc = (lane & 3) * 8;
  const ushortt* pa0 = A + (size_t)(bm + wave * 16 + sr) * K + sc;
  const ushortt* pa1 = pa0 + (size_t)64 * K;
  const ushortt* pb0 = W + (size_t)(bn + wave * 16 + sr) * K + sc;
  const ushortt* pb1 = pb0 + (size_t)64 * K;
  const int lo0 = (wave * 16) * 32;
  const int lo1 = (64 + wave * 16) * 32;

  const int fr = lane & 15;
  const int fq = (lane >> 4) * 8;
  const int nt = K >> 5;

  auto stage = [&](int t, int buf) {
    const int ko = t * 32;
    short* ab = &As[0][0] + buf * 4096;
    short* bb = &Bs[0][0] + buf * 4096;
    __builtin_amdgcn_global_load_lds(
        (const __attribute__((address_space(1))) void*)(pa0 + ko),
        (__attribute__((address_space(3))) void*)(ab + lo0), 16, 0, 0);
    __builtin_amdgcn_global_load_lds(
        (const __attribute__((address_space(1))) void*)(pa1 + ko),
        (__attribute__((address_space(3))) void*)(ab + lo1), 16, 0, 0);
    __builtin_amdgcn_global_load_lds(
        (const __attribute__((address_space(1))) void*)(pb0 + ko),
        (__attribute__((address_space(3))) void*)(bb + lo0), 16, 0, 0);
    __builtin_amdgcn_global_load_lds(
        (const __attribute__((address_space(1))) void*)(pb1 + ko),
        (__attribute__((address_space(3))) void*)(bb + lo1), 16, 0, 0);
  };

  stage(0, 0);
  __syncthreads();

  for (int t = 0; t < nt; ++t) {
    if (t + 1 < nt) stage(t + 1, (t + 1) & 1);
    const short* as = &As[0][0] + (t & 1) * 4096;
    const short* bs = &Bs[0][0] + (t & 1) * 4096;

    frag8 af[4], bf[4];
#pragma unroll
    for (int mi = 0; mi < 4; ++mi)
      af[mi] = *(const frag8*)&as[(wm + mi * 16 + fr) * 32 + fq];
#pragma unroll
    for (int ni = 0; ni < 4; ++ni)
      bf[ni] = *(const frag8*)&bs[(wn + ni * 16 + fr) * 32 + fq];
#pragma unroll
    for (int mi = 0; mi < 4; ++mi)
#pragma unroll
      for (int ni = 0; ni < 4; ++ni)
        acc[mi][ni] = __builtin_amdgcn_mfma_f32_16x16x32_bf16(
            af[mi], bf[ni], acc[mi][ni], 0, 0, 0);
    __syncthreads();
  }

  const int er = (lane >> 4) * 4;
  const int ec = lane & 15;
#pragma unroll
  for (int mi = 0; mi < 4; ++mi)
#pragma unroll
    for (int ni = 0; ni < 4; ++ni)
#pragma unroll
      for (int r = 0; r < 4; ++r) {
        int m = bm + wm + mi * 16 + er + r;
        int n = bn + wn + ni * 16 + ec;
        size_t o = (size_t)m * N + n;
        float v = acc[mi][ni][r];
        if (EPI == 0) {
          ((float*)Cv)[o] = v;
        } else {
          ((ushortt*)Cv)[o] = f2bu(v);
        }
      }
}

// ---------------------------------------------------------------------------
// Fused gate+lin GEMM: one staged A tile feeds TWO B tiles, 32 MFMA/K-step,
// dual accumulators. Epilogue: out = sigmoid(g+gbias)*(l+lbias) -> bf16.
// 1D grid of 512 blocks (2/CU) with xcd_decode: co-resident pair shares by.
// ---------------------------------------------------------------------------
__global__ __launch_bounds__(256) void gemm_gatelin(
    const ushortt* __restrict__ A, const ushortt* __restrict__ Wg,
    const ushortt* __restrict__ Wl, ushortt* __restrict__ Cv,
    const float* __restrict__ gbias, const float* __restrict__ lbias,
    int M, int N, int K) {
  __shared__ __align__(16) short As[2][128 * 32];
  __shared__ __align__(16) short Gs[2][128 * 32];
  __shared__ __align__(16) short Ls[2][128 * 32];
  const int tid = threadIdx.x;
  const int wave = tid >> 6;
  const int lane = tid & 63;
  int bx, by;
  xcd_decode(blockIdx.x, bx, by);
  const int bm = by * 128;
  const int bn = bx * 128;
  const int wm = (wave >> 1) * 64;
  const int wn = (wave & 1) * 64;

  f32x4 accg[4][4] = {};
  f32x4 accl[4][4] = {};

  const int sr = lane >> 2;
  const int sc = (lane & 3) * 8;
  const ushortt* pa0 = A + (size_t)(bm + wave * 16 + sr) * K + sc;
  const ushortt* pa1 = pa0 + (size_t)64 * K;
  const ushortt* pg0 = Wg + (size_t)(bn + wave * 16 + sr) * K + sc;
  const ushortt* pg1 = pg0 + (size_t)64 * K;
  const ushortt* pl0 = Wl + (size_t)(bn + wave * 16 + sr) * K + sc;
  const ushortt* pl1 = pl0 + (size_t)64 * K;
  const int lo0 = (wave * 16) * 32;
  const int lo1 = (64 + wave * 16) * 32;

  const int fr = lane & 15;
  const int fq = (lane >> 4) * 8;
  const int nt = K >> 5;

  auto stage = [&](int t, int buf) {
    const int ko = t * 32;
    short* ab = &As[0][0] + buf * 4096;
    short* gb = &Gs[0][0] + buf * 4096;
    short* lb = &Ls[0][0] + buf * 4096;
    __builtin_amdgcn_global_load_lds(
        (const __attribute__((address_space(1))) void*)(pa0 + ko),
        (__attribute__((address_space(3))) void*)(ab + lo0), 16, 0, 0);
    __builtin_amdgcn_global_load_lds(
        (const __attribute__((address_space(1))) void*)(pa1 + ko),
        (__attribute__((address_space(3))) void*)(ab + lo1), 16, 0, 0);
    __builtin_amdgcn_global_load_lds(
        (const __attribute__((address_space(1))) void*)(pg0 + ko),
        (__attribute__((address_space(3))) void*)(gb + lo0), 16, 0, 0);
    __builtin_amdgcn_global_load_lds(
        (const __attribute__((address_space(1))) void*)(pg1 + ko),
        (__attribute__((address_space(3))) void*)(gb + lo1), 16, 0, 0);
    __builtin_amdgcn_global_load_lds(
        (const __attribute__((address_space(1))) void*)(pl0 + ko),
        (__attribute__((address_space(3))) void*)(lb + lo0), 16, 0, 0);
    __builtin_amdgcn_global_load_lds(
        (const __attribute__((address_space(1))) void*)(pl1 + ko),
        (__attribute__((address_space(3))) void*)(lb + lo1), 16, 0, 0);
  };

  stage(0, 0);
  __syncthreads();

  for (int t = 0; t < nt; ++t) {
    if (t + 1 < nt) stage(t + 1, (t + 1) & 1);
    const short* as = &As[0][0] + (t & 1) * 4096;
    const short* gs = &Gs[0][0] + (t & 1) * 4096;
    const short* ls = &Ls[0][0] + (t & 1) * 4096;

    frag8 af[4], gf[4], lf[4];
#pragma unroll
    for (int mi = 0; mi < 4; ++mi)
      af[mi] = *(const frag8*)&as[(wm + mi * 16 + fr) * 32 + fq];
#pragma unroll
    for (int ni = 0; ni < 4; ++ni) {
      gf[ni] = *(const frag8*)&gs[(wn + ni * 16 + fr) * 32 + fq];
      lf[ni] = *(const frag8*)&ls[(wn + ni * 16 + fr) * 32 + fq];
    }
#pragma unroll
    for (int mi = 0; mi < 4; ++mi)
#pragma unroll
      for (int ni = 0; ni < 4; ++ni) {
        accg[mi][ni] = __builtin_amdgcn_mfma_f32_16x16x32_bf16(
            af[mi], gf[ni], accg[mi][ni], 0, 0, 0);
        accl[mi][ni] = __builtin_amdgcn_mfma_f32_16x16x32_bf16(
            af[mi], lf[ni], accl[mi][ni], 0, 0, 0);
      }
    __syncthreads();
  }

  const int er = (lane >> 4) * 4;
  const int ec = lane & 15;
#pragma unroll
  for (int mi = 0; mi < 4; ++mi)
#pragma unroll
    for (int ni = 0; ni < 4; ++ni)
#pragma unroll
      for (int r = 0; r < 4; ++r) {
        int m = bm + wm + mi * 16 + er + r;
        int n = bn + wn + ni * 16 + ec;
        size_t o = (size_t)m * N + n;
        float g = accg[mi][ni][r] + gbias[n];
        float l = accl[mi][ni][r] + lbias[n];
        float sig = 1.0f / (1.0f + __expf(-g));
        ((ushortt*)Cv)[o] = f2bu(sig * l);
      }
}

// ---------------------------------------------------------------------------
// FF-out GEMM with on-the-fly fp32->bf16 B staging. 1D grid + xcd_decode.
// A = ffc bf16 [M][2048]; B = ff_out_w fp32 [1024][FFDIM] k-offset koff.
// C = proj2 fp32, accumulate across the 2 K-chunks (first ? = : +=).
// ---------------------------------------------------------------------------
__global__ __launch_bounds__(256) void gemm_ffout(
    const ushortt* __restrict__ A, const float* __restrict__ Bw,
    float* __restrict__ C, int lda, int koff, int first) {
  __shared__ __align__(16) short As[2][128 * 32];
  __shared__ __align__(16) short Bs[2][128 * 32];
  const int tid = threadIdx.x;
  const int wave = tid >> 6;
  const int lane = tid & 63;
  int bx, by;
  xcd_decode(blockIdx.x, bx, by);
  const int bm = by * 128;
  const int bn = bx * 128;
  const int wm = (wave >> 1) * 64;
  const int wn = (wave & 1) * 64;

  f32x4 acc[4][4] = {};

  const int sr = lane >> 2;
  const int sc = (lane & 3) * 8;
  const ushortt* pa0 = A + (size_t)(bm + wave * 16 + sr) * lda + sc;
  const ushortt* pa1 = pa0 + (size_t)64 * lda;
  const int lo0 = (wave * 16) * 32;
  const int lo1 = (64 + wave * 16) * 32;

  const int br = tid >> 2;         // B row within tile (0..63, +64)
  const int kc = (tid & 3) * 8;    // k-part within the 32-k step
  const float* pb0 = Bw + (size_t)(bn + br) * FFDIM + koff + kc;
  const float* pb1 = pb0 + (size_t)64 * FFDIM;

  const int fr = lane & 15;
  const int fq = (lane >> 4) * 8;
  const int nt = 2048 >> 5;  // 64

  float4 f0, f1, f2, f3;
  auto bload = [&](int t) {
    const float* p0 = pb0 + t * 32;
    const float* p1 = pb1 + t * 32;
    f0 = *(const float4*)p0; f1 = *(const float4*)(p0 + 4);
    f2 = *(const float4*)p1; f3 = *(const float4*)(p1 + 4);
  };
  auto pk = [&](float4 a, float4 b) {
    frag8 v;
    v[0] = (short)f2bu(a.x); v[1] = (short)f2bu(a.y);
    v[2] = (short)f2bu(a.z); v[3] = (short)f2bu(a.w);
    v[4] = (short)f2bu(b.x); v[5] = (short)f2bu(b.y);
    v[6] = (short)f2bu(b.z); v[7] = (short)f2bu(b.w);
    return v;
  };
  auto bwrite = [&](int buf) {
    *(frag8*)&Bs[buf][tid * 8] = pk(f0, f1);
    *(frag8*)&Bs[buf][2048 + tid * 8] = pk(f2, f3);
  };
  auto astage = [&](int t, int buf) {
    const int ko = t * 32;
    short* ab = &As[0][0] + buf * 4096;
    __builtin_amdgcn_global_load_lds(
        (const __attribute__((address_space(1))) void*)(pa0 + ko),
        (__attribute__((address_space(3))) void*)(ab + lo0), 16, 0, 0);
    __builtin_amdgcn_global_load_lds(
        (const __attribute__((address_space(1))) void*)(pa1 + ko),
        (__attribute__((address_space(3))) void*)(ab + lo1), 16, 0, 0);
  };

  astage(0, 0);
  bload(0);
  bwrite(0);
  __syncthreads();

  for (int t = 0; t < nt; ++t) {
    if (t + 1 < nt) {
      astage(t + 1, (t + 1) & 1);
      bload(t + 1);
    }
    const short* as = &As[0][0] + (t & 1) * 4096;
    const short* bs = &Bs[0][0] + (t & 1) * 4096;

    frag8 af[4], bf[4];
#pragma unroll
    for (int mi = 0; mi < 4; ++mi)
      af[mi] = *(const frag8*)&as[(wm + mi * 16 + fr) * 32 + fq];
#pragma unroll
    for (int ni = 0; ni < 4; ++ni)
      bf[ni] = *(const frag8*)&bs[(wn + ni * 16 + fr) * 32 + fq];
#pragma unroll
    for (int mi = 0; mi < 4; ++mi)
#pragma unroll
      for (int ni = 0; ni < 4; ++ni)
        acc[mi][ni] = __builtin_amdgcn_mfma_f32_16x16x32_bf16(
            af[mi], bf[ni], acc[mi][ni], 0, 0, 0);
    if (t + 1 < nt) bwrite((t + 1) & 1);
    __syncthreads();
  }

  const int er = (lane >> 4) * 4;
  const int ec = lane & 15;
#pragma unroll
  for (int mi = 0; mi < 4; ++mi)
#pragma unroll
    for (int ni = 0; ni < 4; ++ni)
#pragma unroll
      for (int r = 0; r < 4; ++r) {
        int m = bm + wm + mi * 16 + er + r;
        int n = bn + wn + ni * 16 + ec;
        size_t o = (size_t)m * 1024 + n;
        float v = acc[mi][ni][r];
        C[o] = first ? v : C[o] + v;
      }
}

// ---------------------------------------------------------------------------
// RoPE prep: qkv (B,S,3,H,D) bf16 -> Qr,Kr [bh][S][64] (Q scaled 1/8),
// Vr chunk-blocked [bh][S/64][64 d][64 key] (transposed per 64-seq chunk).
// ---------------------------------------------------------------------------
__global__ __launch_bounds__(256) void rope_prep(
    const ushortt* __restrict__ qkv, ushortt* __restrict__ Qr,
    ushortt* __restrict__ Kr, ushortt* __restrict__ Vr) {
  const int s0 = blockIdx.x * 64;
  const int bh = blockIdx.y;
  const int b = bh >> 4, h = bh & 15;
  const int tid = threadIdx.x;
  __shared__ float ifr_s[32];
  __shared__ ushortt vt[64][72];
  if (tid < 32) ifr_s[tid] = __powf(10000.0f, -(float)tid * (1.0f / 32.0f));
  __syncthreads();
  const size_t qbase = (size_t)bh * SEQ * 64;

#pragma unroll
  for (int i = 0; i < 8; ++i) {
    int p = i * 256 + tid;
    int r = p >> 5, d = p & 31;
    size_t src = ((size_t)(b * SEQ + s0 + r)) * (3 * DIMSZ) + h * 64 + d;
    float q1 = u2f(qkv[src]), q2 = u2f(qkv[src + 32]);
    float k1 = u2f(qkv[src + DIMSZ]), k2 = u2f(qkv[src + DIMSZ + 32]);
    float ang = (float)(s0 + r) * ifr_s[d];
    float sn, cs;
    __sincosf(ang, &sn, &cs);
    size_t dst = qbase + (size_t)(s0 + r) * 64 + d;
    Qr[dst]      = f2bu((q1 * cs - q2 * sn) * 0.125f);
    Qr[dst + 32] = f2bu((q1 * sn + q2 * cs) * 0.125f);
    Kr[dst]      = f2bu(k1 * cs - k2 * sn);
    Kr[dst + 32] = f2bu(k1 * sn + k2 * cs);
  }

#pragma unroll
  for (int i = 0; i < 2; ++i) {
    int e = (i * 256 + tid) * 8;
    int r = e >> 6, d0 = e & 63;
    size_t src = ((size_t)(b * SEQ + s0 + r)) * (3 * DIMSZ) + 2 * DIMSZ + h * 64 + d0;
    *(ushort4*)&vt[r][d0]     = *(const ushort4*)(qkv + src);
    *(ushort4*)&vt[r][d0 + 4] = *(const ushort4*)(qkv + src + 4);
  }
  __syncthreads();
  {
    int d = tid >> 2;
    int sc0 = (tid & 3) * 16;
    size_t dst = (size_t)bh * 64 * SEQ + (size_t)blockIdx.x * 4096 +
                 (size_t)d * 64 + sc0;
    ushortt tmp[16];
#pragma unroll
    for (int j = 0; j < 16; ++j) tmp[j] = vt[sc0 + j][d];
    *(ushort4*)(Vr + dst)      = *(ushort4*)&tmp[0];
    *(ushort4*)(Vr + dst + 4)  = *(ushort4*)&tmp[4];
    *(ushort4*)(Vr + dst + 8)  = *(ushort4*)&tmp[8];
    *(ushort4*)(Vr + dst + 12) = *(ushort4*)&tmp[12];
  }
}

// ---------------------------------------------------------------------------
// MFMA flash attention, LDS-staged K/V with double-buffered prefetch.
// 1D grid of 512 blocks; decode pairs qt q with 15-q across halves: per-CU
// cost constant (34), same bh on both co-resident blocks (L2 sharing).
// XOR-swizzle byte^=((row&7)<<4) on both sides (rule #21).
// ---------------------------------------------------------------------------
__global__ __launch_bounds__(512) void flash_mfma(
    const ushortt* __restrict__ Qr, const ushortt* __restrict__ Kr,
    const ushortt* __restrict__ Vr, ushortt* __restrict__ ctx) {
  const int id = blockIdx.x;
  const int r5 = id & 255;
  const int qt0 = r5 >> 5;
  const int qt = (id & 256) ? (15 - qt0) : qt0;   // balanced pairing
  const int bh = r5 & 31;
  const int q0 = qt * 128;
  const int b = bh >> 4, h = bh & 15;
  const int tid = threadIdx.x;
  const int w = tid >> 6;
  const int lane = tid & 63;
  const int fr = lane & 15;
  const int quad = lane >> 4;

  __shared__ __align__(16) short Kb[2][4096];
  __shared__ __align__(16) short Vb[2][4096];
  __shared__ __align__(16) ushortt Ps[8][16][72];

  const size_t qkbase = (size_t)bh * SEQ * 64;
  const size_t vbase = (size_t)bh * 64 * SEQ;

  const int lin = (w << 10) + ((lane & 63) << 4);
  const int swz = lin ^ (((lin >> 7) & 7) << 4);
  const char* ksrc = (const char*)(Kr + qkbase) + swz;
  const char* vsrc = (const char*)(Vr + vbase) + swz;
  short* kdst[2] = {&Kb[0][w * 512], &Kb[1][w * 512]};
  short* vdst[2] = {&Vb[0][w * 512], &Vb[1][w * 512]};

  frag8 aq[2];
#pragma unroll
  for (int hh = 0; hh < 2; ++hh)
    aq[hh] = *(const frag8*)(Qr + qkbase + (size_t)(q0 + w * 16 + fr) * 64 +
                             hh * 32 + quad * 8);

  float mr[4], lr[4];
  f32x4 od[4] = {};
#pragma unroll
  for (int r = 0; r < 4; ++r) { mr[r] = -1e30f; lr[r] = 0.0f; }

  const int nt = 2 * qt + 2;

  __builtin_amdgcn_global_load_lds(
      (const __attribute__((address_space(1))) void*)ksrc,
      (__attribute__((address_space(3))) void*)kdst[0], 16, 0, 0);
  __builtin_amdgcn_global_load_lds(
      (const __attribute__((address_space(1))) void*)vsrc,
      (__attribute__((address_space(3))) void*)vdst[0], 16, 0, 0);
  __syncthreads();

  for (int t = 0; t < nt; ++t) {
    const int c0 = t * 64;
    if (t + 1 < nt) {
      const char* kn = ksrc + (size_t)(t + 1) * 8192;
      const char* vn = vsrc + (size_t)(t + 1) * 8192;
      __builtin_amdgcn_global_load_lds(
          (const __attribute__((address_space(1))) void*)kn,
          (__attribute__((address_space(3))) void*)kdst[(t + 1) & 1], 16, 0, 0);
      __builtin_amdgcn_global_load_lds(
          (const __attribute__((address_space(1))) void*)vn,
          (__attribute__((address_space(3))) void*)vdst[(t + 1) & 1], 16, 0, 0);
    }
    const char* kcur = (const char*)Kb[t & 1];
    const char* vcur = (const char*)Vb[t & 1];

    if (c0 <= q0 + w * 16 + 15) {
      f32x4 sc[4] = {};
#pragma unroll
      for (int ni = 0; ni < 4; ++ni)
#pragma unroll
        for (int hh = 0; hh < 2; ++hh) {
          int kb = (((ni * 16 + fr) << 7) + (hh << 6) + (quad << 4)) ^
                   ((fr & 7) << 4);
          frag8 kf = *(const frag8*)(kcur + kb);
          sc[ni] = __builtin_amdgcn_mfma_f32_16x16x32_bf16(aq[hh], kf, sc[ni],
                                                           0, 0, 0);
        }

      if (c0 + 63 > q0 + w * 16) {
        int rowb = q0 + w * 16 + quad * 4;
#pragma unroll
        for (int ni = 0; ni < 4; ++ni) {
          int col = c0 + ni * 16 + fr;
#pragma unroll
          for (int r = 0; r < 4; ++r)
            if (col > rowb + r) sc[ni][r] = -1e30f;
        }
      }

#pragma unroll
      for (int r = 0; r < 4; ++r) {
        float cm = fmaxf(fmaxf(sc[0][r], sc[1][r]), fmaxf(sc[2][r], sc[3][r]));
        for (int off = 1; off < 16; off <<= 1)
          cm = fmaxf(cm, __shfl_xor(cm, off, 16));
        float mn = fmaxf(mr[r], cm);
        float corr = __expf(mr[r] - mn);
        mr[r] = mn;
        float ps = 0.0f;
#pragma unroll
        for (int ni = 0; ni < 4; ++ni) {
          float p = __expf(sc[ni][r] - mn);
          Ps[w][quad * 4 + r][ni * 16 + fr] = f2bu(p);
          ps += p;
        }
        for (int off = 1; off < 16; off <<= 1) ps += __shfl_xor(ps, off, 16);
        lr[r] = lr[r] * corr + ps;
#pragma unroll
        for (int dt = 0; dt < 4; ++dt) od[dt][r] *= corr;
      }

      frag8 pf[2];
#pragma unroll
      for (int hh = 0; hh < 2; ++hh)
        pf[hh] = *(const frag8*)&Ps[w][fr][hh * 32 + quad * 8];
#pragma unroll
      for (int dt = 0; dt < 4; ++dt)
#pragma unroll
        for (int hh = 0; hh < 2; ++hh) {
          int vb_ = (((dt * 16 + fr) << 7) + (hh << 6) + (quad << 4)) ^
                    ((fr & 7) << 4);
          frag8 vf = *(const frag8*)(vcur + vb_);
          od[dt] = __builtin_amdgcn_mfma_f32_16x16x32_bf16(pf[hh], vf, od[dt],
                                                           0, 0, 0);
        }
    }
    __syncthreads();
  }

#pragma unroll
  for (int r = 0; r < 4; ++r) {
    float inv = 1.0f / lr[r];
    size_t row = (size_t)(b * SEQ + q0 + w * 16 + quad * 4 + r) * DIMSZ + h * 64;
#pragma unroll
    for (int dt = 0; dt < 4; ++dt)
      ctx[row + dt * 16 + fr] = f2bu(od[dt][r] * inv);
  }
}

// ---------------------------------------------------------------------------
// y = res + proj; out = scale * y / (||y||*D^-0.5 + eps). One block per row.
// DUAL=1 also writes bf16 copy (GEMM A operand).
// ---------------------------------------------------------------------------
template <int DUAL>
__global__ __launch_bounds__(256) void add_rmsnorm(
    const float* __restrict__ res, const float* __restrict__ proj,
    const float* __restrict__ scale, float* __restrict__ out,
    ushortt* __restrict__ out2) {
  const int row = blockIdx.x;
  const int tid = threadIdx.x;
  const size_t base = (size_t)row * DIMSZ;
  __shared__ float red[4];
  float y[4];
  float ss = 0.0f;
#pragma unroll
  for (int j = 0; j < 4; ++j) {
    int d = tid + j * 256;
    float yv = res[base + d] + proj[base + d];
    y[j] = yv;
    ss += yv * yv;
  }
  for (int off = 1; off < 64; off <<= 1) ss += __shfl_xor(ss, off, 64);
  if ((tid & 63) == 0) red[tid >> 6] = ss;
  __syncthreads();
  float tot = red[0] + red[1] + red[2] + red[3];
  float norm = sqrtf(tot) * 0.03125f;
  float inv = 1.0f / (norm + 1e-8f);
#pragma unroll
  for (int j = 0; j < 4; ++j) {
    int d = tid + j * 256;
    float v = scale[d] * y[j] * inv;
    out[base + d] = v;
    if (DUAL) out2[base + d] = f2bu(v);
  }
}

// ---------------------------------------------------------------------------
extern "C" void kernel_launch(void* const* d_in, const int* in_sizes, int n_in,
                              void* d_out, int out_size, void* d_ws, size_t ws_size,
                              hipStream_t stream) {
  const float* x          = (const float*)d_in[0];
  // d_in[1] = causal mask (bool) — structure hardcoded, unused
  const float* qkv_w      = (const float*)d_in[2];
  const float* attn_out_w = (const float*)d_in[3];
  const float* gate_w     = (const float*)d_in[4];
  const float* gate_b     = (const float*)d_in[5];
  const float* lin_w      = (const float*)d_in[6];
  const float* lin_b      = (const float*)d_in[7];
  const float* ff_out_w   = (const float*)d_in[8];
  const float* n1s        = (const float*)d_in[9];
  const float* n2s        = (const float*)d_in[10];
  float* out = (float*)d_out;

  const int M = NBATCH * SEQ;  // 4096
  char* ws = (char*)d_ws;
  char* dob = (char*)d_out;
  const size_t MB = 1 << 20;
  // ws layout (bytes), lifetime-disjoint; high-water 48 MB:
  ushortt* qkv_tmp = (ushortt*)(ws + 0);        // [0,24)  bf16, p1..rope
  ushortt* xb      = (ushortt*)(ws + 24 * MB);  // [24,32) bf16, p1 (pre-Qr)
  ushortt* qkv_wb  = (ushortt*)(ws + 32 * MB);  // [32,38) bf16, p1 (pre-Kr)
  ushortt* Qr      = (ushortt*)(ws + 24 * MB);  // [24,32) bf16, rope..attn
  ushortt* Kr      = (ushortt*)(ws + 32 * MB);  // [32,40) bf16, rope..attn
  ushortt* Vr      = (ushortt*)(ws + 40 * MB);  // [40,48) bf16, rope..attn
  ushortt* attn_wb = (ushortt*)(ws + 24 * MB);  // [24,26) bf16, p3 (Qr dead)
  float*   proj    = (float*)(ws + 0);          // [0,16)  fp32, p3..p4
  float*   x1      = (float*)(ws + 16 * MB);    // [16,32) fp32, p4..end
  ushortt* x1b     = (ushortt*)(ws + 32 * MB);  // [32,40) bf16, p4..end
  float*   proj2   = (float*)(ws + 0);          // [0,16)  fp32, p5..end
  ushortt* gcb     = (ushortt*)(ws + 40 * MB);  // [40,44) bf16, p5 chunk
  ushortt* lcb     = (ushortt*)(ws + 44 * MB);  // [44,48)
  // d_out doubles as scratch:
  ushortt* ctx  = (ushortt*)(dob + 0);          // [0,8)  bf16, p2..p3
  ushortt* ffc  = (ushortt*)(dob + 0);          // [0,16) bf16, p5 chunk

  // p1: casts + qkv GEMM (bf16 out)
  cast_f2b<<<4194304 / 1024, 256, 0, stream>>>(x, xb, 4194304);
  cast_f2b<<<3145728 / 1024, 256, 0, stream>>>(qkv_w, qkv_wb, 3145728);
  gemm_mfma<1><<<(3072 / 128) * (M / 128), 256, 0, stream>>>(
      xb, qkv_wb, qkv_tmp, M, 3072, DIMSZ);
  // p2: RoPE prep + MFMA flash attention (balanced 1D grid)
  rope_prep<<<dim3(SEQ / 64, NBATCH * NHEAD), 256, 0, stream>>>(
      qkv_tmp, Qr, Kr, Vr);
  flash_mfma<<<(SEQ / 128) * NBATCH * NHEAD, 512, 0, stream>>>(
      Qr, Kr, Vr, ctx);
  // p3: attn projection (fp32 out)
  cast_f2b<<<1048576 / 1024, 256, 0, stream>>>(attn_out_w, attn_wb, 1048576);
  gemm_mfma<0><<<(DIMSZ / 128) * (M / 128), 256, 0, stream>>>(
      ctx, attn_wb, proj, M, DIMSZ, DIMSZ);
  // p4: x1 = rmsnorm(x + proj), fp32 + bf16 copies
  add_rmsnorm<1><<<M, 256, 0, stream>>>(x, proj, n1s, x1, x1b);
  // p5: FF in 2 chunks of 2048 (all GEMMs XCD-decoded)
  for (int c = 0; c < 2; ++c) {
    cast_f2b<<<2048, 256, 0, stream>>>(
        gate_w + (size_t)c * 2097152, gcb, 2097152);
    cast_f2b<<<2048, 256, 0, stream>>>(
        lin_w + (size_t)c * 2097152, lcb, 2097152);
    gemm_gatelin<<<(2048 / 128) * (M / 128), 256, 0, stream>>>(
        x1b, gcb, lcb, ffc, gate_b + c * 2048, lin_b + c * 2048,
        M, 2048, DIMSZ);
    gemm_ffout<<<(1024 / 128) * (M / 128), 256, 0, stream>>>(
        ffc, ff_out_w, proj2, 2048, c * 2048, c == 0 ? 1 : 0);
  }
  // p6: out = rmsnorm(x1 + proj2)
  add_rmsnorm<0><<<M, 256, 0, stream>>>(x1, proj2, n2s, out, nullptr);
}